// Round 1
// baseline (767.686 us; speedup 1.0000x reference)
//
#include <hip/hip_runtime.h>
#include <cmath>

// Problem constants (fixed by reference)
constexpr int Dd = 1024;   // embed dim
constexpr int Bn = 64;     // n_image == n_caption
constexpr int Sr = 36;     // regions
constexpr int Lm = 32;     // max caption length
constexpr float SMOOTH = 9.0f;
constexpr float LLSE   = 6.0f;
constexpr float EPSF   = 1e-8f;

// ---------------------------------------------------------------------------
// GEMM: C[m*ldc + n] = sum_k A[m*K+k] * B[n*K+k]   (C = A @ B^T)
// 128x128 tile, BK=16, 256 threads, 8x8 micro-tile per thread. fp32 VALU.
// ---------------------------------------------------------------------------
constexpr int TS = 128;
constexpr int KB = 16;

__global__ __launch_bounds__(256) void gemm_abt(
    const float* __restrict__ A, const float* __restrict__ Bm,
    float* __restrict__ C, int K, int ldc)
{
  __shared__ float As[KB][TS];
  __shared__ float Bs[KB][TS];
  const int tid = threadIdx.x;
  const int m0 = blockIdx.y * TS;
  const int n0 = blockIdx.x * TS;
  const int tx = tid & 15;          // n-dir
  const int ty = tid >> 4;          // m-dir
  const int r0 = tid >> 2;          // staging row 0..63
  const int kq = (tid & 3) << 2;    // staging k-quad

  float acc[8][8];
#pragma unroll
  for (int i = 0; i < 8; i++)
#pragma unroll
    for (int j = 0; j < 8; j++) acc[i][j] = 0.f;

  const float* Arow0 = A + (size_t)(m0 + r0) * K + kq;
  const float* Arow1 = A + (size_t)(m0 + 64 + r0) * K + kq;
  const float* Brow0 = Bm + (size_t)(n0 + r0) * K + kq;
  const float* Brow1 = Bm + (size_t)(n0 + 64 + r0) * K + kq;

  for (int k0 = 0; k0 < K; k0 += KB) {
    float4 a0 = *(const float4*)(Arow0 + k0);
    float4 a1 = *(const float4*)(Arow1 + k0);
    float4 b0 = *(const float4*)(Brow0 + k0);
    float4 b1 = *(const float4*)(Brow1 + k0);
    __syncthreads();  // previous-iter LDS reads done before overwrite
    As[kq+0][r0]    = a0.x; As[kq+1][r0]    = a0.y; As[kq+2][r0]    = a0.z; As[kq+3][r0]    = a0.w;
    As[kq+0][64+r0] = a1.x; As[kq+1][64+r0] = a1.y; As[kq+2][64+r0] = a1.z; As[kq+3][64+r0] = a1.w;
    Bs[kq+0][r0]    = b0.x; Bs[kq+1][r0]    = b0.y; Bs[kq+2][r0]    = b0.z; Bs[kq+3][r0]    = b0.w;
    Bs[kq+0][64+r0] = b1.x; Bs[kq+1][64+r0] = b1.y; Bs[kq+2][64+r0] = b1.z; Bs[kq+3][64+r0] = b1.w;
    __syncthreads();
#pragma unroll
    for (int k = 0; k < KB; k++) {
      // split 8 m-rows / 8 n-cols into two 4-wide halves (64 apart) so the
      // b128 LDS reads land 2-way-per-bank (free) instead of 4-way.
      float4 aA = *(const float4*)&As[k][ty*4];
      float4 aB = *(const float4*)&As[k][64+ty*4];
      float4 bA = *(const float4*)&Bs[k][tx*4];
      float4 bB = *(const float4*)&Bs[k][64+tx*4];
      float av[8] = {aA.x,aA.y,aA.z,aA.w,aB.x,aB.y,aB.z,aB.w};
      float bv[8] = {bA.x,bA.y,bA.z,bA.w,bB.x,bB.y,bB.z,bB.w};
#pragma unroll
      for (int i = 0; i < 8; i++)
#pragma unroll
        for (int j = 0; j < 8; j++) acc[i][j] += av[i]*bv[j];
    }
  }
#pragma unroll
  for (int ih = 0; ih < 2; ih++)
#pragma unroll
    for (int ii = 0; ii < 4; ii++) {
      int i = ih*4 + ii;
      int m = m0 + ih*64 + ty*4 + ii;
      float* crow = C + (size_t)m * ldc + n0;
      float4 v0 = make_float4(acc[i][0], acc[i][1], acc[i][2], acc[i][3]);
      float4 v1 = make_float4(acc[i][4], acc[i][5], acc[i][6], acc[i][7]);
      *(float4*)(crow + tx*4) = v0;
      *(float4*)(crow + 64 + tx*4) = v1;
    }
}

// ---------------------------------------------------------------------------
// Gram_b[s][s'] = img_b[s] . img_b[s']   (64 blocks, one per image)
// ---------------------------------------------------------------------------
__global__ __launch_bounds__(256) void gram_kernel(
    const float* __restrict__ img, float* __restrict__ G)
{
  const int b = blockIdx.x;
  __shared__ float tile[Sr][128];
  const int tid = threadIdx.x;
  float acc[6] = {0.f,0.f,0.f,0.f,0.f,0.f};
  for (int c = 0; c < Dd/128; c++) {
    for (int i = tid; i < Sr*128; i += 256) {
      int s = i >> 7, k = i & 127;
      tile[s][k] = img[(size_t)(b*Sr+s)*Dd + c*128 + k];
    }
    __syncthreads();
#pragma unroll
    for (int q = 0; q < 6; q++) {
      int p = q*256 + tid;
      if (p < Sr*Sr) {
        int s = p / 36, s2 = p % 36;
        const float4* ra = (const float4*)tile[s];
        const float4* rb = (const float4*)tile[s2];
#pragma unroll 8
        for (int k4 = 0; k4 < 32; k4++) {
          float4 a = ra[k4], bq = rb[k4];
          acc[q] += a.x*bq.x + a.y*bq.y + a.z*bq.z + a.w*bq.w;
        }
      }
    }
    __syncthreads();
  }
#pragma unroll
  for (int q = 0; q < 6; q++) {
    int p = q*256 + tid;
    if (p < Sr*Sr) G[(size_t)b*Sr*Sr + p] = acc[q];
  }
}

// ---------------------------------------------------------------------------
// w1[cap*Lm + l] = || captions[cap][l] ||   (one wave per row)
// ---------------------------------------------------------------------------
__global__ __launch_bounds__(256) void w1_kernel(
    const float* __restrict__ cap, float* __restrict__ w1)
{
  int wid = threadIdx.x >> 6, lane = threadIdx.x & 63;
  int r = blockIdx.x * 4 + wid;              // 0..2047
  const float* row = cap + (size_t)r * Dd;
  float s = 0.f;
#pragma unroll
  for (int j = 0; j < Dd/64; j++) { float x = row[lane + (j<<6)]; s += x*x; }
#pragma unroll
  for (int o = 32; o; o >>= 1) s += __shfl_xor(s, o);
  if (lane == 0) w1[r] = sqrtf(s);
}

// ---------------------------------------------------------------------------
// Finalize: one block per (image b, caption cap).
// leaky-relu -> mask -> l2norm over l -> softmax over s -> w12/w2 via Gram
// -> cosine -> LogSumExp over valid words.
// ---------------------------------------------------------------------------
__global__ __launch_bounds__(256) void finalize_kernel(
    const float* __restrict__ Cbig, const float* __restrict__ G,
    const float* __restrict__ w1arr, const int* __restrict__ lens,
    float* __restrict__ out)
{
  const int b   = blockIdx.x;   // image index
  const int cap = blockIdx.y;   // caption index
  const int tid = threadIdx.x;
  __shared__ float att[Sr][Lm+1];
  __shared__ float cim[Sr][Lm+1];
  __shared__ float Gs[Sr][Sr+1];
  __shared__ float w12s[Lm], w2s[Lm];

  const int len = lens[cap];

  for (int i = tid; i < Sr*Lm; i += 256) {
    int s = i >> 5, l = i & 31;
    size_t row = (size_t)(b*Sr+s) * 4096;
    float x = Cbig[row + cap*Lm + l];
    x = x > 0.f ? x : 0.1f*x;          // LeakyReLU(0.1)
    if (l >= len) x = 0.f;             // mask padded words
    att[s][l] = x;
    cim[s][l] = Cbig[row + 2048 + cap*Lm + l];
  }
  for (int i = tid; i < Sr*Sr; i += 256)
    Gs[i/36][i%36] = G[(size_t)b*Sr*Sr + i];
  __syncthreads();

  // l2 norm over word dim per region s
  if (tid < Sr) {
    float ss = 0.f;
#pragma unroll
    for (int l = 0; l < Lm; l++) { float v = att[tid][l]; ss += v*v; }
    float inv = 1.f / (sqrtf(ss) + EPSF);
#pragma unroll
    for (int l = 0; l < Lm; l++) att[tid][l] *= inv;
  }
  __syncthreads();

  // softmax over regions s per word l, temperature SMOOTH
  if (tid < Lm) {
    int l = tid;
    float m = -1e30f;
#pragma unroll
    for (int s = 0; s < Sr; s++) m = fmaxf(m, att[s][l]);
    m *= SMOOTH;
    float sum = 0.f;
#pragma unroll
    for (int s = 0; s < Sr; s++) {
      float e = expf(SMOOTH*att[s][l] - m);
      att[s][l] = e; sum += e;
    }
    float inv = 1.f/sum;
#pragma unroll
    for (int s = 0; s < Sr; s++) att[s][l] *= inv;
  }
  __syncthreads();

  // w12[l] = sum_s a.cim ;  w2^2[l] = a^T Gram a   (8 threads per l)
  {
    int l = tid >> 3, g = tid & 7;
    float w12 = 0.f, w2 = 0.f;
    for (int s = g; s < Sr; s += 8) {
      float a = att[s][l];
      w12 += a * cim[s][l];
      float t = 0.f;
#pragma unroll
      for (int s2 = 0; s2 < Sr; s2++) t += Gs[s][s2]*att[s2][l];
      w2 += a * t;
    }
#pragma unroll
    for (int o = 4; o; o >>= 1) { w12 += __shfl_down(w12, o, 8); w2 += __shfl_down(w2, o, 8); }
    if (g == 0) { w12s[l] = w12; w2s[l] = sqrtf(fmaxf(w2, 0.f)); }
  }
  __syncthreads();

  if (tid < Lm) {
    int l = tid;
    float w1 = w1arr[cap*Lm + l];
    float denom = fmaxf(w1 * w2s[l], EPSF);   // clip(w1*w2, EPS, None)
    float rs = w12s[l] / denom;
    float z = (l < len) ? rs * LLSE : -1e30f;
    float m = z;
#pragma unroll
    for (int o = 16; o; o >>= 1) m = fmaxf(m, __shfl_xor(m, o, 32));
    float e = expf(z - m);
#pragma unroll
    for (int o = 16; o; o >>= 1) e += __shfl_xor(e, o, 32);
    if (tid == 0) out[(size_t)b*Bn + cap] = (m + logf(e)) / LLSE;
  }
}

// ---------------------------------------------------------------------------
extern "C" void kernel_launch(void* const* d_in, const int* in_sizes, int n_in,
                              void* d_out, int out_size, void* d_ws, size_t ws_size,
                              hipStream_t stream)
{
  const float* images   = (const float*)d_in[0];  // (64,36,1024)
  const float* captions = (const float*)d_in[1];  // (64,32,1024)
  const int*   cap_lens = (const int*)d_in[2];    // (64,)
  const float* W_g      = (const float*)d_in[3];  // (1024,1024)
  float* out = (float*)d_out;                     // (64,64)

  // Workspace layout (floats): 44.3 MB total
  float* E    = (float*)d_ws;                       // 2048*1024
  float* Cbig = E + (size_t)2048*1024;              // 2304*4096: [:, :2048]=attn_raw, [:, 2048:]=capimg
  float* Gram = Cbig + (size_t)2304*4096;           // 64*36*36
  float* w1a  = Gram + (size_t)Bn*Sr*Sr;            // 2048

  // E = captions_flat @ W_g^T          (M=2048, N=1024, K=1024)
  gemm_abt<<<dim3(1024/TS, 2048/TS), 256, 0, stream>>>(captions, W_g, E, Dd, 1024);
  // Cbig[:, :2048] = images_flat @ E^T (M=2304, N=2048, K=1024)
  gemm_abt<<<dim3(2048/TS, 2304/TS), 256, 0, stream>>>(images, E, Cbig, Dd, 4096);
  // Cbig[:, 2048:] = images_flat @ captions_flat^T
  gemm_abt<<<dim3(2048/TS, 2304/TS), 256, 0, stream>>>(images, captions, Cbig + 2048, Dd, 4096);
  // Gram matrices + caption word norms
  gram_kernel<<<Bn, 256, 0, stream>>>(images, Gram);
  w1_kernel<<<2048/4, 256, 0, stream>>>(captions, w1a);
  // Per (image, caption) finalize
  finalize_kernel<<<dim3(Bn, Bn), 256, 0, stream>>>(Cbig, Gram, w1a, cap_lens, out);
}

// Round 2
// 338.462 us; speedup vs baseline: 2.2682x; 2.2682x over previous
//
#include <hip/hip_runtime.h>
#include <cmath>

// Problem constants (fixed by reference)
constexpr int Dd = 1024;   // embed dim
constexpr int Bn = 64;     // n_image == n_caption
constexpr int Sr = 36;     // regions
constexpr int Lm = 32;     // max caption length
constexpr float SMOOTH = 9.0f;
constexpr float LLSE   = 6.0f;
constexpr float EPSF   = 1e-8f;

using frag_ab = __attribute__((ext_vector_type(8))) short;  // 8 bf16 (4 VGPRs)
using frag_cd = __attribute__((ext_vector_type(4))) float;  // 4 fp32 acc

__device__ inline short f2bf(float f) {            // RNE fp32 -> bf16
  union { float f; unsigned u; } v{f};
  unsigned r = v.u + 0x7FFF + ((v.u >> 16) & 1);
  return (short)(r >> 16);
}
__device__ inline float bf2f(short h) {
  union { unsigned u; float f; } v;
  v.u = ((unsigned)(unsigned short)h) << 16;
  return v.f;
}

__device__ inline void gload16(const short* g, short* l) {
  // async global->LDS, 16B/lane; LDS dest = wave-uniform base + lane*16
  __builtin_amdgcn_global_load_lds(
      (__attribute__((address_space(1))) void*)g,
      (__attribute__((address_space(3))) void*)l, 16, 0, 0);
}

// ---------------------------------------------------------------------------
// fp32 -> bf16 conversion, 4 elems/thread
// ---------------------------------------------------------------------------
__global__ __launch_bounds__(256) void conv_bf16(
    const float* __restrict__ in, short* __restrict__ out, int n)
{
  int i = (blockIdx.x * 256 + threadIdx.x) * 4;
  if (i < n) {
    float4 v = *(const float4*)(in + i);
    short4 o;
    o.x = f2bf(v.x); o.y = f2bf(v.y); o.z = f2bf(v.z); o.w = f2bf(v.w);
    *(short4*)(out + i) = o;
  }
}

// ---------------------------------------------------------------------------
// bf16 MFMA GEMM: C = A @ B^T, A (M x K) row-major bf16, B (N x K) row-major
// bf16, C (M x ldc) bf16. 128x128 tile, BK=32, 256 threads (4 waves, 2x2),
// 16x16x32 MFMA, 4x4 frags/wave. m97-style single-buffer + global_load_lds.
// ---------------------------------------------------------------------------
__global__ __launch_bounds__(256) void mfma_gemm_abt(
    const short* __restrict__ A, const short* __restrict__ B,
    short* __restrict__ C, int K, int ldc)
{
  __shared__ __align__(16) short As[128 * 32];
  __shared__ __align__(16) short Bs[128 * 32];

  const int t    = threadIdx.x;
  const int lane = t & 63;
  const int w    = t >> 6;          // wave 0..3
  const int wm   = w >> 1;          // wave m-half
  const int wn   = w & 1;           // wave n-half
  const int m0 = blockIdx.y * 128;
  const int n0 = blockIdx.x * 128;

  // staging: thread t covers (row = t>>2, kseg = t&3) for rows 0..63 (j=0)
  // and rows 64..127 (j=1); LDS slot = (t + j*256)*8 shorts = lane-contiguous
  const int srow = t >> 2;
  const int skq  = (t & 3) * 8;
  const short* gA0 = A + (size_t)(m0 + srow) * K + skq;
  const short* gA1 = A + (size_t)(m0 + 64 + srow) * K + skq;
  const short* gB0 = B + (size_t)(n0 + srow) * K + skq;
  const short* gB1 = B + (size_t)(n0 + 64 + srow) * K + skq;
  short* lA0 = As + w * 512;
  short* lA1 = As + 2048 + w * 512;
  short* lB0 = Bs + w * 512;
  short* lB1 = Bs + 2048 + w * 512;

  // fragment read addresses: A[m=lane&15][k=quad*8+j], row-major LDS (32/row)
  const int fr = lane & 15;
  const int fq = lane >> 4;
  const short* aAddr = As + (wm * 64 + fr) * 32 + fq * 8;
  const short* bAddr = Bs + (wn * 64 + fr) * 32 + fq * 8;

  frag_cd acc[4][4] = {};

  for (int k0 = 0; k0 < K; k0 += 32) {
    __syncthreads();                 // prev-iter LDS readers done
    gload16(gA0 + k0, lA0);
    gload16(gA1 + k0, lA1);
    gload16(gB0 + k0, lB0);
    gload16(gB1 + k0, lB1);
    __syncthreads();                 // staging drained (barrier waits vmcnt 0)

    frag_ab af[4], bfr[4];
#pragma unroll
    for (int i = 0; i < 4; i++) af[i]  = *(const frag_ab*)(aAddr + i * 512);
#pragma unroll
    for (int j = 0; j < 4; j++) bfr[j] = *(const frag_ab*)(bAddr + j * 512);
#pragma unroll
    for (int i = 0; i < 4; i++)
#pragma unroll
      for (int j = 0; j < 4; j++)
        acc[i][j] = __builtin_amdgcn_mfma_f32_16x16x32_bf16(
            af[i], bfr[j], acc[i][j], 0, 0, 0);
  }

  // C/D layout: col = lane&15, row = (lane>>4)*4 + reg  [verified m89/m91]
#pragma unroll
  for (int i = 0; i < 4; i++) {
    int row = m0 + wm * 64 + i * 16 + fq * 4;
#pragma unroll
    for (int j = 0; j < 4; j++) {
      int col = n0 + wn * 64 + j * 16 + fr;
#pragma unroll
      for (int r = 0; r < 4; r++)
        C[(size_t)(row + r) * ldc + col] = f2bf(acc[i][j][r]);
    }
  }
}

// ---------------------------------------------------------------------------
// Gram_b[s][s'] = img_b[s] . img_b[s']  (fp32, exact) — 64 blocks
// ---------------------------------------------------------------------------
__global__ __launch_bounds__(256) void gram_kernel(
    const float* __restrict__ img, float* __restrict__ G)
{
  const int b = blockIdx.x;
  __shared__ float tile[Sr][128];
  const int tid = threadIdx.x;
  float acc[6] = {0.f, 0.f, 0.f, 0.f, 0.f, 0.f};
  for (int c = 0; c < Dd / 128; c++) {
    for (int i = tid; i < Sr * 128; i += 256) {
      int s = i >> 7, k = i & 127;
      tile[s][k] = img[(size_t)(b * Sr + s) * Dd + c * 128 + k];
    }
    __syncthreads();
#pragma unroll
    for (int q = 0; q < 6; q++) {
      int p = q * 256 + tid;
      if (p < Sr * Sr) {
        int s = p / 36, s2 = p % 36;
        const float4* ra = (const float4*)tile[s];
        const float4* rb = (const float4*)tile[s2];
#pragma unroll 8
        for (int k4 = 0; k4 < 32; k4++) {
          float4 a = ra[k4], bq = rb[k4];
          acc[q] += a.x * bq.x + a.y * bq.y + a.z * bq.z + a.w * bq.w;
        }
      }
    }
    __syncthreads();
  }
#pragma unroll
  for (int q = 0; q < 6; q++) {
    int p = q * 256 + tid;
    if (p < Sr * Sr) G[(size_t)b * Sr * Sr + p] = acc[q];
  }
}

// ---------------------------------------------------------------------------
// w1[cap*Lm + l] = || captions[cap][l] ||  (fp32 exact, one wave per row)
// ---------------------------------------------------------------------------
__global__ __launch_bounds__(256) void w1_kernel(
    const float* __restrict__ cap, float* __restrict__ w1)
{
  int wid = threadIdx.x >> 6, lane = threadIdx.x & 63;
  int r = blockIdx.x * 4 + wid;
  const float* row = cap + (size_t)r * Dd;
  float s = 0.f;
#pragma unroll
  for (int j = 0; j < Dd / 64; j++) { float x = row[lane + (j << 6)]; s += x * x; }
#pragma unroll
  for (int o = 32; o; o >>= 1) s += __shfl_xor(s, o);
  if (lane == 0) w1[r] = sqrtf(s);
}

// ---------------------------------------------------------------------------
// Finalize: one block per (image b, caption cap). Cbig is bf16:
// [:, :2048] = attn_raw, [:, 2048:] = capimg, row stride 4096.
// ---------------------------------------------------------------------------
__global__ __launch_bounds__(256) void finalize_kernel(
    const short* __restrict__ Cbig, const float* __restrict__ G,
    const float* __restrict__ w1arr, const int* __restrict__ lens,
    float* __restrict__ out)
{
  const int b   = blockIdx.x;
  const int cap = blockIdx.y;
  const int tid = threadIdx.x;
  __shared__ float att[Sr][Lm + 1];
  __shared__ float cim[Sr][Lm + 1];
  __shared__ float Gs[Sr][Sr + 1];
  __shared__ float w12s[Lm], w2s[Lm];

  const int len = lens[cap];

  for (int i = tid; i < Sr * Lm; i += 256) {
    int s = i >> 5, l = i & 31;
    size_t row = (size_t)(b * Sr + s) * 4096;
    float x = bf2f(Cbig[row + cap * Lm + l]);
    x = x > 0.f ? x : 0.1f * x;        // LeakyReLU(0.1)
    if (l >= len) x = 0.f;             // mask padded words
    att[s][l] = x;
    cim[s][l] = bf2f(Cbig[row + 2048 + cap * Lm + l]);
  }
  for (int i = tid; i < Sr * Sr; i += 256)
    Gs[i / 36][i % 36] = G[(size_t)b * Sr * Sr + i];
  __syncthreads();

  if (tid < Sr) {                      // l2 norm over word dim per region
    float ss = 0.f;
#pragma unroll
    for (int l = 0; l < Lm; l++) { float v = att[tid][l]; ss += v * v; }
    float inv = 1.f / (sqrtf(ss) + EPSF);
#pragma unroll
    for (int l = 0; l < Lm; l++) att[tid][l] *= inv;
  }
  __syncthreads();

  if (tid < Lm) {                      // softmax over regions per word
    int l = tid;
    float m = -1e30f;
#pragma unroll
    for (int s = 0; s < Sr; s++) m = fmaxf(m, att[s][l]);
    m *= SMOOTH;
    float sum = 0.f;
#pragma unroll
    for (int s = 0; s < Sr; s++) {
      float e = expf(SMOOTH * att[s][l] - m);
      att[s][l] = e; sum += e;
    }
    float inv = 1.f / sum;
#pragma unroll
    for (int s = 0; s < Sr; s++) att[s][l] *= inv;
  }
  __syncthreads();

  {                                    // w12, w2 via Gram (8 threads per l)
    int l = tid >> 3, g = tid & 7;
    float w12 = 0.f, w2 = 0.f;
    for (int s = g; s < Sr; s += 8) {
      float a = att[s][l];
      w12 += a * cim[s][l];
      float tt = 0.f;
#pragma unroll
      for (int s2 = 0; s2 < Sr; s2++) tt += Gs[s][s2] * att[s2][l];
      w2 += a * tt;
    }
#pragma unroll
    for (int o = 4; o; o >>= 1) { w12 += __shfl_down(w12, o, 8); w2 += __shfl_down(w2, o, 8); }
    if (g == 0) { w12s[l] = w12; w2s[l] = sqrtf(fmaxf(w2, 0.f)); }
  }
  __syncthreads();

  if (tid < Lm) {
    int l = tid;
    float w1 = w1arr[cap * Lm + l];
    float denom = fmaxf(w1 * w2s[l], EPSF);
    float rs = w12s[l] / denom;
    float z = (l < len) ? rs * LLSE : -1e30f;
    float m = z;
#pragma unroll
    for (int o = 16; o; o >>= 1) m = fmaxf(m, __shfl_xor(m, o, 32));
    float e = expf(z - m);
#pragma unroll
    for (int o = 16; o; o >>= 1) e += __shfl_xor(e, o, 32);
    if (tid == 0) out[(size_t)b * Bn + cap] = (m + logf(e)) / LLSE;
  }
}

// ---------------------------------------------------------------------------
extern "C" void kernel_launch(void* const* d_in, const int* in_sizes, int n_in,
                              void* d_out, int out_size, void* d_ws, size_t ws_size,
                              hipStream_t stream)
{
  const float* images   = (const float*)d_in[0];  // (64,36,1024)
  const float* captions = (const float*)d_in[1];  // (64,32,1024)
  const int*   cap_lens = (const int*)d_in[2];    // (64,)
  const float* W_g      = (const float*)d_in[3];  // (1024,1024)
  float* out = (float*)d_out;                     // (64,64)

  // Workspace (~34.4 MB):
  short* imgbf = (short*)d_ws;                          // 2304*1024 bf16
  short* Bcat  = imgbf + (size_t)2304 * 1024;           // 4096*1024 bf16: [0:2048)=E, [2048:4096)=captions
  short* capbf = Bcat + (size_t)2048 * 1024;
  short* Wbf   = Bcat + (size_t)4096 * 1024;            // 1024*1024 bf16
  short* Cbig  = Wbf + (size_t)1024 * 1024;             // 2304*4096 bf16
  float* Gram  = (float*)(Cbig + (size_t)2304 * 4096);  // 64*36*36 fp32
  float* w1a   = Gram + (size_t)Bn * Sr * Sr;           // 2048 fp32

  conv_bf16<<<2304, 256, 0, stream>>>(images, imgbf, 2304 * 1024);
  conv_bf16<<<2048, 256, 0, stream>>>(captions, capbf, 2048 * 1024);
  conv_bf16<<<1024, 256, 0, stream>>>(W_g, Wbf, 1024 * 1024);

  // E = captions @ W_g^T  (2048 x 1024 x 1024) -> Bcat[0:2048)
  mfma_gemm_abt<<<dim3(1024 / 128, 2048 / 128), 256, 0, stream>>>(
      capbf, Wbf, Bcat, Dd, 1024);
  // Cbig = images @ Bcat^T  (2304 x 4096 x 1024): attn_raw | capimg fused
  mfma_gemm_abt<<<dim3(4096 / 128, 2304 / 128), 256, 0, stream>>>(
      imgbf, Bcat, Cbig, Dd, 4096);

  gram_kernel<<<Bn, 256, 0, stream>>>(images, Gram);
  w1_kernel<<<2048 / 4, 256, 0, stream>>>(captions, w1a);
  finalize_kernel<<<dim3(Bn, Bn), 256, 0, stream>>>(Cbig, Gram, w1a, cap_lens, out);
}

// Round 3
// 180.960 us; speedup vs baseline: 4.2423x; 1.8704x over previous
//
#include <hip/hip_runtime.h>
#include <cmath>

// Problem constants (fixed by reference)
constexpr int Dd = 1024;   // embed dim
constexpr int Bn = 64;     // n_image == n_caption
constexpr int Sr = 36;     // regions
constexpr int Lm = 32;     // max caption length
constexpr float SMOOTH = 9.0f;
constexpr float LLSE   = 6.0f;
constexpr float EPSF   = 1e-8f;

using frag_ab = __attribute__((ext_vector_type(8))) short;  // 8 bf16 (4 VGPRs)
using frag_cd = __attribute__((ext_vector_type(4))) float;  // 4 fp32 acc

__device__ inline short f2bf(float f) {            // RNE fp32 -> bf16
  union { float f; unsigned u; } v{f};
  unsigned r = v.u + 0x7FFF + ((v.u >> 16) & 1);
  return (short)(r >> 16);
}
__device__ inline float bf2f(short h) {
  union { unsigned u; float f; } v;
  v.u = ((unsigned)(unsigned short)h) << 16;
  return v.f;
}

__device__ inline void gload16(const short* g, short* l) {
  // async global->LDS, 16B/lane; LDS dest = wave-uniform base + lane*16
  __builtin_amdgcn_global_load_lds(
      (__attribute__((address_space(1))) void*)g,
      (__attribute__((address_space(3))) void*)l, 16, 0, 0);
}

// ---------------------------------------------------------------------------
// fp32 -> bf16 for two arrays in one dispatch (images, W_g)
// ---------------------------------------------------------------------------
__global__ __launch_bounds__(256) void conv_two(
    const float* __restrict__ a, short* __restrict__ oa, int na,
    const float* __restrict__ b, short* __restrict__ ob, int nb)
{
  int i = (blockIdx.x * 256 + threadIdx.x) * 4;
  const float* src; short* dst;
  if (i < na) { src = a + i; dst = oa + i; }
  else { int j = i - na; if (j >= nb) return; src = b + j; dst = ob + j; }
  float4 v = *(const float4*)src;
  short4 o;
  o.x = f2bf(v.x); o.y = f2bf(v.y); o.z = f2bf(v.z); o.w = f2bf(v.w);
  *(short4*)dst = o;
}

// ---------------------------------------------------------------------------
// captions: fp32 -> bf16 conversion fused with per-row l2 norm (w1).
// One block per row (1024 elems = 256 threads x float4).
// ---------------------------------------------------------------------------
__global__ __launch_bounds__(256) void conv_cap_w1(
    const float* __restrict__ cap, short* __restrict__ out,
    float* __restrict__ w1)
{
  const int r = blockIdx.x;               // 0..2047
  const int tid = threadIdx.x;
  __shared__ float wsum[4];
  float4 v = *(const float4*)(cap + (size_t)r * Dd + tid * 4);
  short4 o;
  o.x = f2bf(v.x); o.y = f2bf(v.y); o.z = f2bf(v.z); o.w = f2bf(v.w);
  *(short4*)(out + (size_t)r * Dd + tid * 4) = o;
  float s = v.x * v.x + v.y * v.y + v.z * v.z + v.w * v.w;
#pragma unroll
  for (int off = 32; off; off >>= 1) s += __shfl_xor(s, off);
  if ((tid & 63) == 0) wsum[tid >> 6] = s;
  __syncthreads();
  if (tid == 0) w1[r] = sqrtf(wsum[0] + wsum[1] + wsum[2] + wsum[3]);
}

// ---------------------------------------------------------------------------
// bf16 MFMA GEMM: C = A @ B^T (bf16 in, bf16 out), 128x128 tile, BK=32,
// 256 threads, 16x16x32 MFMA, 4x4 frags/wave, global_load_lds staging.
// ---------------------------------------------------------------------------
__global__ __launch_bounds__(256) void mfma_gemm_abt(
    const short* __restrict__ A, const short* __restrict__ B,
    short* __restrict__ C, int K, int ldc)
{
  __shared__ __align__(16) short As[128 * 32];
  __shared__ __align__(16) short Bs[128 * 32];

  const int t    = threadIdx.x;
  const int lane = t & 63;
  const int w    = t >> 6;
  const int wm   = w >> 1;
  const int wn   = w & 1;
  const int m0 = blockIdx.y * 128;
  const int n0 = blockIdx.x * 128;

  const int srow = t >> 2;
  const int skq  = (t & 3) * 8;
  const short* gA0 = A + (size_t)(m0 + srow) * K + skq;
  const short* gA1 = A + (size_t)(m0 + 64 + srow) * K + skq;
  const short* gB0 = B + (size_t)(n0 + srow) * K + skq;
  const short* gB1 = B + (size_t)(n0 + 64 + srow) * K + skq;
  short* lA0 = As + w * 512;
  short* lA1 = As + 2048 + w * 512;
  short* lB0 = Bs + w * 512;
  short* lB1 = Bs + 2048 + w * 512;

  const int fr = lane & 15;
  const int fq = lane >> 4;
  const short* aAddr = As + (wm * 64 + fr) * 32 + fq * 8;
  const short* bAddr = Bs + (wn * 64 + fr) * 32 + fq * 8;

  frag_cd acc[4][4] = {};

  for (int k0 = 0; k0 < K; k0 += 32) {
    __syncthreads();
    gload16(gA0 + k0, lA0);
    gload16(gA1 + k0, lA1);
    gload16(gB0 + k0, lB0);
    gload16(gB1 + k0, lB1);
    __syncthreads();

    frag_ab af[4], bfr[4];
#pragma unroll
    for (int i = 0; i < 4; i++) af[i]  = *(const frag_ab*)(aAddr + i * 512);
#pragma unroll
    for (int j = 0; j < 4; j++) bfr[j] = *(const frag_ab*)(bAddr + j * 512);
#pragma unroll
    for (int i = 0; i < 4; i++)
#pragma unroll
      for (int j = 0; j < 4; j++)
        acc[i][j] = __builtin_amdgcn_mfma_f32_16x16x32_bf16(
            af[i], bfr[j], acc[i][j], 0, 0, 0);
  }

  // C/D layout: col = lane&15, row = (lane>>4)*4 + reg  [verified m89/m91]
#pragma unroll
  for (int i = 0; i < 4; i++) {
    int row = m0 + wm * 64 + i * 16 + fq * 4;
#pragma unroll
    for (int j = 0; j < 4; j++) {
      int col = n0 + wn * 64 + j * 16 + fr;
#pragma unroll
      for (int r = 0; r < 4; r++)
        C[(size_t)(row + r) * ldc + col] = f2bf(acc[i][j][r]);
    }
  }
}

// ---------------------------------------------------------------------------
// Gram: one block per (b, s). Row s staged in LDS; each wave streams rows s2
// from global (coalesced, L2-resident) and shuffle-reduces. fp32 exact.
// ---------------------------------------------------------------------------
__global__ __launch_bounds__(256) void gram_kernel(
    const float* __restrict__ img, float* __restrict__ G)
{
  const int blk = blockIdx.x;
  const int b = blk / Sr, s = blk % Sr;
  __shared__ float4 ref[256];
  const int tid = threadIdx.x;
  ref[tid] = ((const float4*)(img + (size_t)(b * Sr + s) * Dd))[tid];
  __syncthreads();
  const int wv = tid >> 6, lane = tid & 63;
  for (int s2 = wv; s2 < Sr; s2 += 4) {
    const float4* row2 = (const float4*)(img + (size_t)(b * Sr + s2) * Dd);
    float acc = 0.f;
#pragma unroll
    for (int j = 0; j < 4; j++) {
      float4 a = ref[lane + j * 64];
      float4 c = row2[lane + j * 64];
      acc += a.x * c.x + a.y * c.y + a.z * c.z + a.w * c.w;
    }
#pragma unroll
    for (int o = 32; o; o >>= 1) acc += __shfl_xor(acc, o);
    if (lane == 0) G[(size_t)b * Sr * Sr + s * Sr + s2] = acc;
  }
}

// ---------------------------------------------------------------------------
// Finalize: one block per (image b, caption cap). Cbig is bf16:
// [:, :2048] = attn_raw, [:, 2048:] = capimg, row stride 4096.
// ---------------------------------------------------------------------------
__global__ __launch_bounds__(256) void finalize_kernel(
    const short* __restrict__ Cbig, const float* __restrict__ G,
    const float* __restrict__ w1arr, const int* __restrict__ lens,
    float* __restrict__ out)
{
  const int b   = blockIdx.x;
  const int cap = blockIdx.y;
  const int tid = threadIdx.x;
  __shared__ float att[Sr][Lm + 1];
  __shared__ float cim[Sr][Lm + 1];
  __shared__ float Gs[Sr][Sr + 1];
  __shared__ float w12s[Lm], w2s[Lm];

  const int len = lens[cap];

  for (int i = tid; i < Sr * Lm; i += 256) {
    int s = i >> 5, l = i & 31;
    size_t row = (size_t)(b * Sr + s) * 4096;
    float x = bf2f(Cbig[row + cap * Lm + l]);
    x = x > 0.f ? x : 0.1f * x;        // LeakyReLU(0.1)
    if (l >= len) x = 0.f;             // mask padded words
    att[s][l] = x;
    cim[s][l] = bf2f(Cbig[row + 2048 + cap * Lm + l]);
  }
  for (int i = tid; i < Sr * Sr; i += 256)
    Gs[i / 36][i % 36] = G[(size_t)b * Sr * Sr + i];
  __syncthreads();

  if (tid < Sr) {                      // l2 norm over word dim per region
    float ss = 0.f;
#pragma unroll
    for (int l = 0; l < Lm; l++) { float v = att[tid][l]; ss += v * v; }
    float inv = 1.f / (sqrtf(ss) + EPSF);
#pragma unroll
    for (int l = 0; l < Lm; l++) att[tid][l] *= inv;
  }
  __syncthreads();

  if (tid < Lm) {                      // softmax over regions per word
    int l = tid;
    float m = -1e30f;
#pragma unroll
    for (int s = 0; s < Sr; s++) m = fmaxf(m, att[s][l]);
    m *= SMOOTH;
    float sum = 0.f;
#pragma unroll
    for (int s = 0; s < Sr; s++) {
      float e = expf(SMOOTH * att[s][l] - m);
      att[s][l] = e; sum += e;
    }
    float inv = 1.f / sum;
#pragma unroll
    for (int s = 0; s < Sr; s++) att[s][l] *= inv;
  }
  __syncthreads();

  {                                    // w12, w2 via Gram (8 threads per l)
    int l = tid >> 3, g = tid & 7;
    float w12 = 0.f, w2 = 0.f;
    for (int s = g; s < Sr; s += 8) {
      float a = att[s][l];
      w12 += a * cim[s][l];
      float tt = 0.f;
#pragma unroll
      for (int s2 = 0; s2 < Sr; s2++) tt += Gs[s][s2] * att[s2][l];
      w2 += a * tt;
    }
#pragma unroll
    for (int o = 4; o; o >>= 1) { w12 += __shfl_down(w12, o, 8); w2 += __shfl_down(w2, o, 8); }
    if (g == 0) { w12s[l] = w12; w2s[l] = sqrtf(fmaxf(w2, 0.f)); }
  }
  __syncthreads();

  if (tid < Lm) {
    int l = tid;
    float w1 = w1arr[cap * Lm + l];
    float denom = fmaxf(w1 * w2s[l], EPSF);
    float rs = w12s[l] / denom;
    float z = (l < len) ? rs * LLSE : -1e30f;
    float m = z;
#pragma unroll
    for (int o = 16; o; o >>= 1) m = fmaxf(m, __shfl_xor(m, o, 32));
    float e = expf(z - m);
#pragma unroll
    for (int o = 16; o; o >>= 1) e += __shfl_xor(e, o, 32);
    if (tid == 0) out[(size_t)b * Bn + cap] = (m + logf(e)) / LLSE;
  }
}

// ---------------------------------------------------------------------------
extern "C" void kernel_launch(void* const* d_in, const int* in_sizes, int n_in,
                              void* d_out, int out_size, void* d_ws, size_t ws_size,
                              hipStream_t stream)
{
  const float* images   = (const float*)d_in[0];  // (64,36,1024)
  const float* captions = (const float*)d_in[1];  // (64,32,1024)
  const int*   cap_lens = (const int*)d_in[2];    // (64,)
  const float* W_g      = (const float*)d_in[3];  // (1024,1024)
  float* out = (float*)d_out;                     // (64,64)

  // Workspace (~34.4 MB):
  short* imgbf = (short*)d_ws;                          // 2304*1024 bf16
  short* Bcat  = imgbf + (size_t)2304 * 1024;           // 4096*1024 bf16: [0:2048)=E, [2048:4096)=captions
  short* capbf = Bcat + (size_t)2048 * 1024;
  short* Wbf   = Bcat + (size_t)4096 * 1024;            // 1024*1024 bf16
  short* Cbig  = Wbf + (size_t)1024 * 1024;             // 2304*4096 bf16
  float* Gram  = (float*)(Cbig + (size_t)2304 * 4096);  // 64*36*36 fp32
  float* w1a   = Gram + (size_t)Bn * Sr * Sr;           // 2048 fp32

  conv_two<<<(2304 * 1024 + 1024 * 1024) / 1024, 256, 0, stream>>>(
      images, imgbf, 2304 * 1024, W_g, Wbf, 1024 * 1024);
  conv_cap_w1<<<2048, 256, 0, stream>>>(captions, capbf, w1a);

  // E = captions @ W_g^T  (2048 x 1024 x 1024) -> Bcat[0:2048)
  mfma_gemm_abt<<<dim3(1024 / 128, 2048 / 128), 256, 0, stream>>>(
      capbf, Wbf, Bcat, Dd, 1024);
  // Cbig = images @ Bcat^T  (2304 x 4096 x 1024): attn_raw | capimg fused
  mfma_gemm_abt<<<dim3(4096 / 128, 2304 / 128), 256, 0, stream>>>(
      imgbf, Bcat, Cbig, Dd, 4096);

  gram_kernel<<<Bn * Sr, 256, 0, stream>>>(images, Gram);
  finalize_kernel<<<dim3(Bn, Bn), 256, 0, stream>>>(Cbig, Gram, w1a, cap_lens, out);
}

// Round 4
// 171.534 us; speedup vs baseline: 4.4754x; 1.0549x over previous
//
#include <hip/hip_runtime.h>
#include <cmath>

// Problem constants (fixed by reference)
constexpr int Dd = 1024;   // embed dim
constexpr int Bn = 64;     // n_image == n_caption
constexpr int Sr = 36;     // regions
constexpr int Lm = 32;     // max caption length
constexpr float SMOOTH = 9.0f;
constexpr float LLSE   = 6.0f;
constexpr float EPSF   = 1e-8f;

using frag_ab = __attribute__((ext_vector_type(8))) short;  // 8 bf16 (4 VGPRs)
using frag_cd = __attribute__((ext_vector_type(4))) float;  // 4 fp32 acc

__device__ inline short f2bf(float f) {            // RNE fp32 -> bf16
  union { float f; unsigned u; } v{f};
  unsigned r = v.u + 0x7FFF + ((v.u >> 16) & 1);
  return (short)(r >> 16);
}
__device__ inline float bf2f(short h) {
  union { unsigned u; float f; } v;
  v.u = ((unsigned)(unsigned short)h) << 16;
  return v.f;
}

__device__ inline void gload16(const short* g, short* l) {
  // async global->LDS, 16B/lane; LDS dest = wave-uniform base + lane*16
  __builtin_amdgcn_global_load_lds(
      (__attribute__((address_space(1))) void*)g,
      (__attribute__((address_space(3))) void*)l, 16, 0, 0);
}

// ---------------------------------------------------------------------------
// fp32 -> bf16 for two arrays in one dispatch (images, W_g)
// ---------------------------------------------------------------------------
__global__ __launch_bounds__(256) void conv_two(
    const float* __restrict__ a, short* __restrict__ oa, int na,
    const float* __restrict__ b, short* __restrict__ ob, int nb)
{
  int i = (blockIdx.x * 256 + threadIdx.x) * 4;
  const float* src; short* dst;
  if (i < na) { src = a + i; dst = oa + i; }
  else { int j = i - na; if (j >= nb) return; src = b + j; dst = ob + j; }
  float4 v = *(const float4*)src;
  short4 o;
  o.x = f2bf(v.x); o.y = f2bf(v.y); o.z = f2bf(v.z); o.w = f2bf(v.w);
  *(short4*)dst = o;
}

// ---------------------------------------------------------------------------
// captions: fp32 -> bf16 conversion fused with per-row l2 norm (w1).
// One block per row (1024 elems = 256 threads x float4).
// ---------------------------------------------------------------------------
__global__ __launch_bounds__(256) void conv_cap_w1(
    const float* __restrict__ cap, short* __restrict__ out,
    float* __restrict__ w1)
{
  const int r = blockIdx.x;               // 0..2047
  const int tid = threadIdx.x;
  __shared__ float wsum[4];
  float4 v = *(const float4*)(cap + (size_t)r * Dd + tid * 4);
  short4 o;
  o.x = f2bf(v.x); o.y = f2bf(v.y); o.z = f2bf(v.z); o.w = f2bf(v.w);
  *(short4*)(out + (size_t)r * Dd + tid * 4) = o;
  float s = v.x * v.x + v.y * v.y + v.z * v.z + v.w * v.w;
#pragma unroll
  for (int off = 32; off; off >>= 1) s += __shfl_xor(s, off);
  if ((tid & 63) == 0) wsum[tid >> 6] = s;
  __syncthreads();
  if (tid == 0) w1[r] = sqrtf(wsum[0] + wsum[1] + wsum[2] + wsum[3]);
}

// ---------------------------------------------------------------------------
// bf16 MFMA GEMM: C = A @ B^T (bf16 in/out). 128x128 tile, BK=64, 256 thr,
// 16x16x32 MFMA, 4x4 frags/wave.
// LDS layout XOR-swizzled: chunk c (8 shorts) of row r stored at position
// c ^ (r&7) within the 64-short row. Staging permutes the GLOBAL chunk each
// lane fetches (global stays coalesced: 8 lanes cover a full 128B row),
// satisfying global_load_lds's fixed lane->slot mapping. Fragment reads then
// hit banks pos*4 mod 32 -> all 8 bank-quads per 16-lane phase, 2 lanes/bank
// = conflict-free (m136: 2-way is free). Old layout was 8-way conflicted.
// ---------------------------------------------------------------------------
__global__ __launch_bounds__(256) void mfma_gemm_abt(
    const short* __restrict__ A, const short* __restrict__ B,
    short* __restrict__ C, int K, int ldc)
{
  __shared__ __align__(16) short As[128 * 64];
  __shared__ __align__(16) short Bs[128 * 64];

  const int t    = threadIdx.x;
  const int lane = t & 63;
  const int w    = t >> 6;
  const int wm   = w >> 1;
  const int wn   = w & 1;
  const int m0 = blockIdx.y * 128;
  const int n0 = blockIdx.x * 128;

  // staging: issue j covers rows j*32..j*32+31; thread t -> rowIn = t>>3,
  // pos = t&7, global chunk = pos ^ (rowIn&7). Slot (j*256+t)*8 shorts.
  const int rIn = t >> 3;
  const int ch  = (t & 7) ^ (rIn & 7);
  const short* gA = A + (size_t)(m0 + rIn) * K + ch * 8;
  const short* gB = B + (size_t)(n0 + rIn) * K + ch * 8;

  // fragment read bases: row = (wm|wn)*64 + i*16 + fr, 64 shorts/row
  const int fr = lane & 15;
  const int fq = lane >> 4;
  const int p0 = fq ^ (fr & 7);         // swizzled chunk position, k-half 0
  const short* aBase = As + (wm * 64 + fr) * 64;
  const short* bBase = Bs + (wn * 64 + fr) * 64;

  frag_cd acc[4][4] = {};

  for (int k0 = 0; k0 < K; k0 += 64) {
    __syncthreads();
#pragma unroll
    for (int j = 0; j < 4; j++) {
      gload16(gA + (size_t)j * 32 * K + k0, As + j * 2048 + w * 512);
      gload16(gB + (size_t)j * 32 * K + k0, Bs + j * 2048 + w * 512);
    }
    __syncthreads();

#pragma unroll
    for (int th = 0; th < 2; th++) {
      const int pa = p0 ^ (th * 4);     // chunk pos for this k-half
      frag_ab af[4], bfr[4];
#pragma unroll
      for (int i = 0; i < 4; i++) af[i]  = *(const frag_ab*)(aBase + i * 1024 + pa * 8);
#pragma unroll
      for (int j = 0; j < 4; j++) bfr[j] = *(const frag_ab*)(bBase + j * 1024 + pa * 8);
#pragma unroll
      for (int i = 0; i < 4; i++)
#pragma unroll
        for (int j = 0; j < 4; j++)
          acc[i][j] = __builtin_amdgcn_mfma_f32_16x16x32_bf16(
              af[i], bfr[j], acc[i][j], 0, 0, 0);
    }
  }

  // C/D layout: col = lane&15, row = (lane>>4)*4 + reg  [verified m89/m91]
#pragma unroll
  for (int i = 0; i < 4; i++) {
    int row = m0 + wm * 64 + i * 16 + fq * 4;
#pragma unroll
    for (int j = 0; j < 4; j++) {
      int col = n0 + wn * 64 + j * 16 + fr;
#pragma unroll
      for (int r = 0; r < 4; r++)
        C[(size_t)(row + r) * ldc + col] = f2bf(acc[i][j][r]);
    }
  }
}

// ---------------------------------------------------------------------------
// Gram: one block per (b, s). Row s staged in LDS; each wave streams rows s2
// from global (coalesced, L2-resident) and shuffle-reduces. fp32 exact.
// ---------------------------------------------------------------------------
__global__ __launch_bounds__(256) void gram_kernel(
    const float* __restrict__ img, float* __restrict__ G)
{
  const int blk = blockIdx.x;
  const int b = blk / Sr, s = blk % Sr;
  __shared__ float4 ref[256];
  const int tid = threadIdx.x;
  ref[tid] = ((const float4*)(img + (size_t)(b * Sr + s) * Dd))[tid];
  __syncthreads();
  const int wv = tid >> 6, lane = tid & 63;
  for (int s2 = wv; s2 < Sr; s2 += 4) {
    const float4* row2 = (const float4*)(img + (size_t)(b * Sr + s2) * Dd);
    float acc = 0.f;
#pragma unroll
    for (int j = 0; j < 4; j++) {
      float4 a = ref[lane + j * 64];
      float4 c = row2[lane + j * 64];
      acc += a.x * c.x + a.y * c.y + a.z * c.z + a.w * c.w;
    }
#pragma unroll
    for (int o = 32; o; o >>= 1) acc += __shfl_xor(acc, o);
    if (lane == 0) G[(size_t)b * Sr * Sr + s * Sr + s2] = acc;
  }
}

// ---------------------------------------------------------------------------
// Finalize: one block per (image b, caption cap). Cbig is bf16:
// [:, :2048] = attn_raw, [:, 2048:] = capimg, row stride 4096.
// ---------------------------------------------------------------------------
__global__ __launch_bounds__(256) void finalize_kernel(
    const short* __restrict__ Cbig, const float* __restrict__ G,
    const float* __restrict__ w1arr, const int* __restrict__ lens,
    float* __restrict__ out)
{
  const int b   = blockIdx.x;
  const int cap = blockIdx.y;
  const int tid = threadIdx.x;
  __shared__ float att[Sr][Lm + 1];
  __shared__ float cim[Sr][Lm + 1];
  __shared__ float Gs[Sr][Sr + 1];
  __shared__ float w12s[Lm], w2s[Lm];

  const int len = lens[cap];

  for (int i = tid; i < Sr * Lm; i += 256) {
    int s = i >> 5, l = i & 31;
    size_t row = (size_t)(b * Sr + s) * 4096;
    float x = bf2f(Cbig[row + cap * Lm + l]);
    x = x > 0.f ? x : 0.1f * x;        // LeakyReLU(0.1)
    if (l >= len) x = 0.f;             // mask padded words
    att[s][l] = x;
    cim[s][l] = bf2f(Cbig[row + 2048 + cap * Lm + l]);
  }
  for (int i = tid; i < Sr * Sr; i += 256)
    Gs[i / 36][i % 36] = G[(size_t)b * Sr * Sr + i];
  __syncthreads();

  if (tid < Sr) {                      // l2 norm over word dim per region
    float ss = 0.f;
#pragma unroll
    for (int l = 0; l < Lm; l++) { float v = att[tid][l]; ss += v * v; }
    float inv = 1.f / (sqrtf(ss) + EPSF);
#pragma unroll
    for (int l = 0; l < Lm; l++) att[tid][l] *= inv;
  }
  __syncthreads();

  if (tid < Lm) {                      // softmax over regions per word
    int l = tid;
    float m = -1e30f;
#pragma unroll
    for (int s = 0; s < Sr; s++) m = fmaxf(m, att[s][l]);
    m *= SMOOTH;
    float sum = 0.f;
#pragma unroll
    for (int s = 0; s < Sr; s++) {
      float e = expf(SMOOTH * att[s][l] - m);
      att[s][l] = e; sum += e;
    }
    float inv = 1.f / sum;
#pragma unroll
    for (int s = 0; s < Sr; s++) att[s][l] *= inv;
  }
  __syncthreads();

  {                                    // w12, w2 via Gram (8 threads per l)
    int l = tid >> 3, g = tid & 7;
    float w12 = 0.f, w2 = 0.f;
    for (int s = g; s < Sr; s += 8) {
      float a = att[s][l];
      w12 += a * cim[s][l];
      float tt = 0.f;
#pragma unroll
      for (int s2 = 0; s2 < Sr; s2++) tt += Gs[s][s2] * att[s2][l];
      w2 += a * tt;
    }
#pragma unroll
    for (int o = 4; o; o >>= 1) { w12 += __shfl_down(w12, o, 8); w2 += __shfl_down(w2, o, 8); }
    if (g == 0) { w12s[l] = w12; w2s[l] = sqrtf(fmaxf(w2, 0.f)); }
  }
  __syncthreads();

  if (tid < Lm) {
    int l = tid;
    float w1 = w1arr[cap * Lm + l];
    float denom = fmaxf(w1 * w2s[l], EPSF);
    float rs = w12s[l] / denom;
    float z = (l < len) ? rs * LLSE : -1e30f;
    float m = z;
#pragma unroll
    for (int o = 16; o; o >>= 1) m = fmaxf(m, __shfl_xor(m, o, 32));
    float e = expf(z - m);
#pragma unroll
    for (int o = 16; o; o >>= 1) e += __shfl_xor(e, o, 32);
    if (tid == 0) out[(size_t)b * Bn + cap] = (m + logf(e)) / LLSE;
  }
}

// ---------------------------------------------------------------------------
extern "C" void kernel_launch(void* const* d_in, const int* in_sizes, int n_in,
                              void* d_out, int out_size, void* d_ws, size_t ws_size,
                              hipStream_t stream)
{
  const float* images   = (const float*)d_in[0];  // (64,36,1024)
  const float* captions = (const float*)d_in[1];  // (64,32,1024)
  const int*   cap_lens = (const int*)d_in[2];    // (64,)
  const float* W_g      = (const float*)d_in[3];  // (1024,1024)
  float* out = (float*)d_out;                     // (64,64)

  // Workspace (~34.4 MB):
  short* imgbf = (short*)d_ws;                          // 2304*1024 bf16
  short* Bcat  = imgbf + (size_t)2304 * 1024;           // 4096*1024 bf16: [0:2048)=E, [2048:4096)=captions
  short* capbf = Bcat + (size_t)2048 * 1024;
  short* Wbf   = Bcat + (size_t)4096 * 1024;            // 1024*1024 bf16
  short* Cbig  = Wbf + (size_t)1024 * 1024;             // 2304*4096 bf16
  float* Gram  = (float*)(Cbig + (size_t)2304 * 4096);  // 64*36*36 fp32
  float* w1a   = Gram + (size_t)Bn * Sr * Sr;           // 2048 fp32

  conv_two<<<(2304 * 1024 + 1024 * 1024) / 1024, 256, 0, stream>>>(
      images, imgbf, 2304 * 1024, W_g, Wbf, 1024 * 1024);
  conv_cap_w1<<<2048, 256, 0, stream>>>(captions, capbf, w1a);

  // E = captions @ W_g^T  (2048 x 1024 x 1024) -> Bcat[0:2048)
  mfma_gemm_abt<<<dim3(1024 / 128, 2048 / 128), 256, 0, stream>>>(
      capbf, Wbf, Bcat, Dd, 1024);
  // Cbig = images @ Bcat^T  (2304 x 4096 x 1024): attn_raw | capimg fused
  mfma_gemm_abt<<<dim3(4096 / 128, 2304 / 128), 256, 0, stream>>>(
      imgbf, Bcat, Cbig, Dd, 4096);

  gram_kernel<<<Bn * Sr, 256, 0, stream>>>(images, Gram);
  finalize_kernel<<<dim3(Bn, Bn), 256, 0, stream>>>(Cbig, Gram, w1a, cap_lens, out);
}

// Round 5
// 168.672 us; speedup vs baseline: 4.5514x; 1.0170x over previous
//
#include <hip/hip_runtime.h>
#include <cmath>

// Problem constants (fixed by reference)
constexpr int Dd = 1024;   // embed dim
constexpr int Bn = 64;     // n_image == n_caption
constexpr int Sr = 36;     // regions
constexpr int Lm = 32;     // max caption length
constexpr float SMOOTH = 9.0f;
constexpr float LLSE   = 6.0f;
constexpr float EPSF   = 1e-8f;

using frag_ab = __attribute__((ext_vector_type(8))) short;  // 8 bf16 (4 VGPRs)
using frag_cd = __attribute__((ext_vector_type(4))) float;  // 4 fp32 acc

__device__ inline short f2bf(float f) {            // RNE fp32 -> bf16
  union { float f; unsigned u; } v{f};
  unsigned r = v.u + 0x7FFF + ((v.u >> 16) & 1);
  return (short)(r >> 16);
}
__device__ inline float bf2f(short h) {
  union { unsigned u; float f; } v;
  v.u = ((unsigned)(unsigned short)h) << 16;
  return v.f;
}

__device__ inline void gload16(const short* g, short* l) {
  // async global->LDS, 16B/lane; LDS dest = wave-uniform base + lane*16
  __builtin_amdgcn_global_load_lds(
      (__attribute__((address_space(1))) void*)g,
      (__attribute__((address_space(3))) void*)l, 16, 0, 0);
}

// ---------------------------------------------------------------------------
// Fused prep: blockIdx ranges
//   [0, 3328)    : fp32->bf16 conversion of images (2304 blk) + W_g (1024 blk)
//   [3328, 5376) : captions conversion fused with per-row l2 norm (w1)
//   [5376, 7680) : Gram rows, one block per (b, s)
// ---------------------------------------------------------------------------
__global__ __launch_bounds__(256) void prep_kernel(
    const float* __restrict__ images, short* __restrict__ imgbf,
    const float* __restrict__ W_g, short* __restrict__ Wbf,
    const float* __restrict__ captions, short* __restrict__ capbf,
    float* __restrict__ w1, float* __restrict__ G)
{
  const int blk = blockIdx.x;
  const int tid = threadIdx.x;
  __shared__ float4 ref[256];
  __shared__ float wsum[4];

  if (blk < 3328) {
    int i = blk * 1024 + tid * 4;
    const float* src; short* dst;
    if (i < 2304 * 1024) { src = images + i; dst = imgbf + i; }
    else { int j = i - 2304 * 1024; src = W_g + j; dst = Wbf + j; }
    float4 v = *(const float4*)src;
    short4 o;
    o.x = f2bf(v.x); o.y = f2bf(v.y); o.z = f2bf(v.z); o.w = f2bf(v.w);
    *(short4*)dst = o;
  } else if (blk < 5376) {
    const int r = blk - 3328;           // caption row 0..2047
    float4 v = *(const float4*)(captions + (size_t)r * Dd + tid * 4);
    short4 o;
    o.x = f2bf(v.x); o.y = f2bf(v.y); o.z = f2bf(v.z); o.w = f2bf(v.w);
    *(short4*)(capbf + (size_t)r * Dd + tid * 4) = o;
    float s = v.x * v.x + v.y * v.y + v.z * v.z + v.w * v.w;
#pragma unroll
    for (int off = 32; off; off >>= 1) s += __shfl_xor(s, off);
    if ((tid & 63) == 0) wsum[tid >> 6] = s;
    __syncthreads();
    if (tid == 0) w1[r] = sqrtf(wsum[0] + wsum[1] + wsum[2] + wsum[3]);
  } else {
    const int p = blk - 5376;
    const int b = p / Sr, s = p % Sr;
    ref[tid] = ((const float4*)(images + (size_t)(b * Sr + s) * Dd))[tid];
    __syncthreads();
    const int wv = tid >> 6, lane = tid & 63;
    for (int s2 = wv; s2 < Sr; s2 += 4) {
      const float4* row2 = (const float4*)(images + (size_t)(b * Sr + s2) * Dd);
      float acc = 0.f;
#pragma unroll
      for (int j = 0; j < 4; j++) {
        float4 a = ref[lane + j * 64];
        float4 c = row2[lane + j * 64];
        acc += a.x * c.x + a.y * c.y + a.z * c.z + a.w * c.w;
      }
#pragma unroll
      for (int o = 32; o; o >>= 1) acc += __shfl_xor(acc, o);
      if (lane == 0) G[(size_t)b * Sr * Sr + s * Sr + s2] = acc;
    }
  }
}

// ---------------------------------------------------------------------------
// bf16 MFMA GEMM, C = A @ B^T (bf16 in/out), templated BMxBN tile, BK=64,
// 256 threads (2x2 waves), 16x16x32 MFMA, DOUBLE-BUFFERED global_load_lds:
// loads for tile k+1 are issued right after the barrier that publishes tile
// k, so their latency overlaps tile-k compute; the next barrier's vmcnt
// drain lands on mostly-complete loads. XOR-swizzled LDS (chunk c of row r
// at position c^(r&7)) keeps fragment ds_read_b128 at 2 lanes/bank (free).
// ---------------------------------------------------------------------------
template <int BM, int BN>
__global__ __launch_bounds__(256) void mfma_gemm_dbuf(
    const short* __restrict__ A, const short* __restrict__ B,
    short* __restrict__ C, int K, int ldc)
{
  constexpr int FI = BM / 32;         // A-frags per wave (m)
  constexpr int FJ = BN / 32;         // B-frags per wave (n)
  __shared__ __align__(16) short LA[2][BM * 64];
  __shared__ __align__(16) short LB[2][BN * 64];

  const int t    = threadIdx.x;
  const int lane = t & 63;
  const int w    = t >> 6;
  const int wm   = w >> 1;
  const int wn   = w & 1;
  const int m0 = blockIdx.y * BM;
  const int n0 = blockIdx.x * BN;

  // staging: issue j covers 32 rows; thread t -> row t>>3, stores global
  // chunk (t&7)^(row&7) at position t&7 (XOR swizzle, global coalesced).
  const int rIn = t >> 3;
  const int ch  = (t & 7) ^ (rIn & 7);
  const short* gA = A + (size_t)(m0 + rIn) * K + ch * 8;
  const short* gB = B + (size_t)(n0 + rIn) * K + ch * 8;

  const int fr = lane & 15;
  const int fq = lane >> 4;
  const int p0 = fq ^ (fr & 7);

  frag_cd acc[FI][FJ] = {};

  auto stage = [&](int buf, int k0) {
#pragma unroll
    for (int j = 0; j < BM / 32; j++)
      gload16(gA + (size_t)j * 32 * K + k0, &LA[buf][j * 2048 + w * 512]);
#pragma unroll
    for (int j = 0; j < BN / 32; j++)
      gload16(gB + (size_t)j * 32 * K + k0, &LB[buf][j * 2048 + w * 512]);
  };

  stage(0, 0);
  int cur = 0;
  for (int k0 = 0; k0 < K; k0 += 64) {
    __syncthreads();                    // drains vmcnt: buf[cur] published;
                                        // also prev compute done -> safe to
                                        // overwrite buf[cur^1] below
    if (k0 + 64 < K) stage(cur ^ 1, k0 + 64);   // in flight during compute

    const short* aBase = &LA[cur][(wm * (FI * 16) + fr) * 64];
    const short* bBase = &LB[cur][(wn * (FJ * 16) + fr) * 64];
#pragma unroll
    for (int th = 0; th < 2; th++) {
      const int pa = p0 ^ (th * 4);     // swizzled chunk pos for this k-half
      frag_ab af[FI], bf[FJ];
#pragma unroll
      for (int i = 0; i < FI; i++)
        af[i] = *(const frag_ab*)(aBase + i * 16 * 64 + pa * 8);
#pragma unroll
      for (int j = 0; j < FJ; j++)
        bf[j] = *(const frag_ab*)(bBase + j * 16 * 64 + pa * 8);
#pragma unroll
      for (int i = 0; i < FI; i++)
#pragma unroll
        for (int j = 0; j < FJ; j++)
          acc[i][j] = __builtin_amdgcn_mfma_f32_16x16x32_bf16(
              af[i], bf[j], acc[i][j], 0, 0, 0);
    }
    cur ^= 1;
  }

  // C/D layout: col = lane&15, row = (lane>>4)*4 + reg  [verified m89/m91]
#pragma unroll
  for (int i = 0; i < FI; i++) {
    int row = m0 + wm * (FI * 16) + i * 16 + fq * 4;
#pragma unroll
    for (int j = 0; j < FJ; j++) {
      int col = n0 + wn * (FJ * 16) + j * 16 + fr;
#pragma unroll
      for (int r = 0; r < 4; r++)
        C[(size_t)(row + r) * ldc + col] = f2bf(acc[i][j][r]);
    }
  }
}

// ---------------------------------------------------------------------------
// Finalize: one block per (image b, caption cap). Cbig is bf16:
// [:, :2048] = attn_raw, [:, 2048:] = capimg, row stride 4096.
// ---------------------------------------------------------------------------
__global__ __launch_bounds__(256) void finalize_kernel(
    const short* __restrict__ Cbig, const float* __restrict__ G,
    const float* __restrict__ w1arr, const int* __restrict__ lens,
    float* __restrict__ out)
{
  const int b   = blockIdx.x;
  const int cap = blockIdx.y;
  const int tid = threadIdx.x;
  __shared__ float att[Sr][Lm + 1];
  __shared__ float cim[Sr][Lm + 1];
  __shared__ float Gs[Sr][Sr + 1];
  __shared__ float w12s[Lm], w2s[Lm];

  const int len = lens[cap];

  for (int i = tid; i < Sr * Lm; i += 256) {
    int s = i >> 5, l = i & 31;
    size_t row = (size_t)(b * Sr + s) * 4096;
    float x = bf2f(Cbig[row + cap * Lm + l]);
    x = x > 0.f ? x : 0.1f * x;        // LeakyReLU(0.1)
    if (l >= len) x = 0.f;             // mask padded words
    att[s][l] = x;
    cim[s][l] = bf2f(Cbig[row + 2048 + cap * Lm + l]);
  }
  for (int i = tid; i < Sr * Sr; i += 256)
    Gs[i / 36][i % 36] = G[(size_t)b * Sr * Sr + i];
  __syncthreads();

  if (tid < Sr) {                      // l2 norm over word dim per region
    float ss = 0.f;
#pragma unroll
    for (int l = 0; l < Lm; l++) { float v = att[tid][l]; ss += v * v; }
    float inv = 1.f / (sqrtf(ss) + EPSF);
#pragma unroll
    for (int l = 0; l < Lm; l++) att[tid][l] *= inv;
  }
  __syncthreads();

  if (tid < Lm) {                      // softmax over regions per word
    int l = tid;
    float m = -1e30f;
#pragma unroll
    for (int s = 0; s < Sr; s++) m = fmaxf(m, att[s][l]);
    m *= SMOOTH;
    float sum = 0.f;
#pragma unroll
    for (int s = 0; s < Sr; s++) {
      float e = expf(SMOOTH * att[s][l] - m);
      att[s][l] = e; sum += e;
    }
    float inv = 1.f / sum;
#pragma unroll
    for (int s = 0; s < Sr; s++) att[s][l] *= inv;
  }
  __syncthreads();

  {                                    // w12, w2 via Gram (8 threads per l)
    int l = tid >> 3, g = tid & 7;
    float w12 = 0.f, w2 = 0.f;
    for (int s = g; s < Sr; s += 8) {
      float a = att[s][l];
      w12 += a * cim[s][l];
      float tt = 0.f;
#pragma unroll
      for (int s2 = 0; s2 < Sr; s2++) tt += Gs[s][s2] * att[s2][l];
      w2 += a * tt;
    }
#pragma unroll
    for (int o = 4; o; o >>= 1) { w12 += __shfl_down(w12, o, 8); w2 += __shfl_down(w2, o, 8); }
    if (g == 0) { w12s[l] = w12; w2s[l] = sqrtf(fmaxf(w2, 0.f)); }
  }
  __syncthreads();

  if (tid < Lm) {
    int l = tid;
    float w1 = w1arr[cap * Lm + l];
    float denom = fmaxf(w1 * w2s[l], EPSF);
    float rs = w12s[l] / denom;
    float z = (l < len) ? rs * LLSE : -1e30f;
    float m = z;
#pragma unroll
    for (int o = 16; o; o >>= 1) m = fmaxf(m, __shfl_xor(m, o, 32));
    float e = expf(z - m);
#pragma unroll
    for (int o = 16; o; o >>= 1) e += __shfl_xor(e, o, 32);
    if (tid == 0) out[(size_t)b * Bn + cap] = (m + logf(e)) / LLSE;
  }
}

// ---------------------------------------------------------------------------
extern "C" void kernel_launch(void* const* d_in, const int* in_sizes, int n_in,
                              void* d_out, int out_size, void* d_ws, size_t ws_size,
                              hipStream_t stream)
{
  const float* images   = (const float*)d_in[0];  // (64,36,1024)
  const float* captions = (const float*)d_in[1];  // (64,32,1024)
  const int*   cap_lens = (const int*)d_in[2];    // (64,)
  const float* W_g      = (const float*)d_in[3];  // (1024,1024)
  float* out = (float*)d_out;                     // (64,64)

  // Workspace (~34.4 MB):
  short* imgbf = (short*)d_ws;                          // 2304*1024 bf16
  short* Bcat  = imgbf + (size_t)2304 * 1024;           // 4096*1024 bf16: [0:2048)=E, [2048:4096)=captions
  short* capbf = Bcat + (size_t)2048 * 1024;
  short* Wbf   = Bcat + (size_t)4096 * 1024;            // 1024*1024 bf16
  short* Cbig  = Wbf + (size_t)1024 * 1024;             // 2304*4096 bf16
  float* Gram  = (float*)(Cbig + (size_t)2304 * 4096);  // 64*36*36 fp32
  float* w1a   = Gram + (size_t)Bn * Sr * Sr;           // 2048 fp32

  // conversions + w1 + gram fused (7680 blocks)
  prep_kernel<<<7680, 256, 0, stream>>>(
      images, imgbf, W_g, Wbf, captions, capbf, w1a, Gram);

  // E = captions @ W_g^T  (2048 x 1024 x 1024), 64x64 tile -> 512 blocks
  mfma_gemm_dbuf<64, 64><<<dim3(1024 / 64, 2048 / 64), 256, 0, stream>>>(
      capbf, Wbf, Bcat, Dd, 1024);
  // Cbig = images @ Bcat^T (2304 x 4096 x 1024), 128x128 tile -> 576 blocks
  mfma_gemm_dbuf<128, 128><<<dim3(4096 / 128, 2304 / 128), 256, 0, stream>>>(
      imgbf, Bcat, Cbig, Dd, 4096);

  finalize_kernel<<<dim3(Bn, Bn), 256, 0, stream>>>(Cbig, Gram, w1a, cap_lens, out);
}

// Round 6
// 160.800 us; speedup vs baseline: 4.7742x; 1.0490x over previous
//
#include <hip/hip_runtime.h>
#include <cmath>

// Problem constants (fixed by reference)
constexpr int Dd = 1024;   // embed dim
constexpr int Bn = 64;     // n_image == n_caption
constexpr int Sr = 36;     // regions
constexpr int Lm = 32;     // max caption length
constexpr float SMOOTH = 9.0f;
constexpr float LLSE   = 6.0f;
constexpr float EPSF   = 1e-8f;

using frag_ab = __attribute__((ext_vector_type(8))) short;  // 8 bf16 (4 VGPRs)
using frag_cd = __attribute__((ext_vector_type(4))) float;  // 4 fp32 acc

__device__ inline short f2bf(float f) {            // RNE fp32 -> bf16
  union { float f; unsigned u; } v{f};
  unsigned r = v.u + 0x7FFF + ((v.u >> 16) & 1);
  return (short)(r >> 16);
}
__device__ inline float bf2f(short h) {
  union { unsigned u; float f; } v;
  v.u = ((unsigned)(unsigned short)h) << 16;
  return v.f;
}

__device__ inline void gload16(const short* g, short* l) {
  // async global->LDS, 16B/lane; LDS dest = wave-uniform base + lane*16
  __builtin_amdgcn_global_load_lds(
      (__attribute__((address_space(1))) void*)g,
      (__attribute__((address_space(3))) void*)l, 16, 0, 0);
}

// ---------------------------------------------------------------------------
// Fused prep: blockIdx ranges
//   [0, 3328)    : fp32->bf16 conversion of images (2304 blk) + W_g (1024 blk)
//   [3328, 5376) : captions conversion fused with per-row l2 norm (w1)
//   [5376, 7680) : Gram rows, one block per (b, s)
// ---------------------------------------------------------------------------
__global__ __launch_bounds__(256) void prep_kernel(
    const float* __restrict__ images, short* __restrict__ imgbf,
    const float* __restrict__ W_g, short* __restrict__ Wbf,
    const float* __restrict__ captions, short* __restrict__ capbf,
    float* __restrict__ w1, float* __restrict__ G)
{
  const int blk = blockIdx.x;
  const int tid = threadIdx.x;
  __shared__ float4 ref[256];
  __shared__ float wsum[4];

  if (blk < 3328) {
    int i = blk * 1024 + tid * 4;
    const float* src; short* dst;
    if (i < 2304 * 1024) { src = images + i; dst = imgbf + i; }
    else { int j = i - 2304 * 1024; src = W_g + j; dst = Wbf + j; }
    float4 v = *(const float4*)src;
    short4 o;
    o.x = f2bf(v.x); o.y = f2bf(v.y); o.z = f2bf(v.z); o.w = f2bf(v.w);
    *(short4*)dst = o;
  } else if (blk < 5376) {
    const int r = blk - 3328;           // caption row 0..2047
    float4 v = *(const float4*)(captions + (size_t)r * Dd + tid * 4);
    short4 o;
    o.x = f2bf(v.x); o.y = f2bf(v.y); o.z = f2bf(v.z); o.w = f2bf(v.w);
    *(short4*)(capbf + (size_t)r * Dd + tid * 4) = o;
    float s = v.x * v.x + v.y * v.y + v.z * v.z + v.w * v.w;
#pragma unroll
    for (int off = 32; off; off >>= 1) s += __shfl_xor(s, off);
    if ((tid & 63) == 0) wsum[tid >> 6] = s;
    __syncthreads();
    if (tid == 0) w1[r] = sqrtf(wsum[0] + wsum[1] + wsum[2] + wsum[3]);
  } else {
    const int p = blk - 5376;
    const int b = p / Sr, s = p % Sr;
    ref[tid] = ((const float4*)(images + (size_t)(b * Sr + s) * Dd))[tid];
    __syncthreads();
    const int wv = tid >> 6, lane = tid & 63;
    for (int s2 = wv; s2 < Sr; s2 += 4) {
      const float4* row2 = (const float4*)(images + (size_t)(b * Sr + s2) * Dd);
      float acc = 0.f;
#pragma unroll
      for (int j = 0; j < 4; j++) {
        float4 a = ref[lane + j * 64];
        float4 c = row2[lane + j * 64];
        acc += a.x * c.x + a.y * c.y + a.z * c.z + a.w * c.w;
      }
#pragma unroll
      for (int o = 32; o; o >>= 1) acc += __shfl_xor(acc, o);
      if (lane == 0) G[(size_t)b * Sr * Sr + s * Sr + s2] = acc;
    }
  }
}

// ---------------------------------------------------------------------------
// bf16 MFMA GEMM, C = A @ B^T (bf16 in/out), templated BMxBN tile, BK=64,
// 256 threads (2x2 waves), 16x16x32 MFMA, double-buffered global_load_lds.
// Narrow tiles (BN=64) raise the grid to >=3 blocks/CU (LDS 48 KB) so 12
// waves/CU hide load latency — R5 showed 128x128 @ 2 blocks/CU was
// latency-bound, with dbuf neutral (m99 replication).
// XOR-swizzled LDS (chunk c of row r at position c^(r&7)): fragment
// ds_read_b128 lands 2 lanes/bank = free (m136); staging permutes the
// GLOBAL chunk per lane (coalesced: 8 lanes cover a 128B row).
// ---------------------------------------------------------------------------
template <int BM, int BN, int MINW>
__global__ __launch_bounds__(256, MINW) void mfma_gemm_dbuf(
    const short* __restrict__ A, const short* __restrict__ B,
    short* __restrict__ C, int K, int ldc)
{
  constexpr int FI = BM / 32;         // A-frags per wave (m)
  constexpr int FJ = BN / 32;         // B-frags per wave (n)
  __shared__ __align__(16) short LA[2][BM * 64];
  __shared__ __align__(16) short LB[2][BN * 64];

  const int t    = threadIdx.x;
  const int lane = t & 63;
  const int w    = t >> 6;
  const int wm   = w >> 1;
  const int wn   = w & 1;
  const int m0 = blockIdx.y * BM;
  const int n0 = blockIdx.x * BN;

  // staging: issue j covers 32 rows; thread t -> row t>>3, stores global
  // chunk (t&7)^(row&7) at position t&7 (XOR swizzle, global coalesced).
  const int rIn = t >> 3;
  const int ch  = (t & 7) ^ (rIn & 7);
  const short* gA = A + (size_t)(m0 + rIn) * K + ch * 8;
  const short* gB = B + (size_t)(n0 + rIn) * K + ch * 8;

  const int fr = lane & 15;
  const int fq = lane >> 4;
  const int p0 = fq ^ (fr & 7);

  frag_cd acc[FI][FJ] = {};

  auto stage = [&](int buf, int k0) {
#pragma unroll
    for (int j = 0; j < BM / 32; j++)
      gload16(gA + (size_t)j * 32 * K + k0, &LA[buf][j * 2048 + w * 512]);
#pragma unroll
    for (int j = 0; j < BN / 32; j++)
      gload16(gB + (size_t)j * 32 * K + k0, &LB[buf][j * 2048 + w * 512]);
  };

  stage(0, 0);
  int cur = 0;
  for (int k0 = 0; k0 < K; k0 += 64) {
    __syncthreads();                    // publishes buf[cur]; prev compute
                                        // done -> safe to refill buf[cur^1]
    if (k0 + 64 < K) stage(cur ^ 1, k0 + 64);   // in flight during compute

    const short* aBase = &LA[cur][(wm * (FI * 16) + fr) * 64];
    const short* bBase = &LB[cur][(wn * (FJ * 16) + fr) * 64];
#pragma unroll
    for (int th = 0; th < 2; th++) {
      const int pa = p0 ^ (th * 4);     // swizzled chunk pos for this k-half
      frag_ab af[FI], bf[FJ];
#pragma unroll
      for (int i = 0; i < FI; i++)
        af[i] = *(const frag_ab*)(aBase + i * 16 * 64 + pa * 8);
#pragma unroll
      for (int j = 0; j < FJ; j++)
        bf[j] = *(const frag_ab*)(bBase + j * 16 * 64 + pa * 8);
#pragma unroll
      for (int i = 0; i < FI; i++)
#pragma unroll
        for (int j = 0; j < FJ; j++)
          acc[i][j] = __builtin_amdgcn_mfma_f32_16x16x32_bf16(
              af[i], bf[j], acc[i][j], 0, 0, 0);
    }
    cur ^= 1;
  }

  // C/D layout: col = lane&15, row = (lane>>4)*4 + reg  [verified m89/m91]
#pragma unroll
  for (int i = 0; i < FI; i++) {
    int row = m0 + wm * (FI * 16) + i * 16 + fq * 4;
#pragma unroll
    for (int j = 0; j < FJ; j++) {
      int col = n0 + wn * (FJ * 16) + j * 16 + fr;
#pragma unroll
      for (int r = 0; r < 4; r++)
        C[(size_t)(row + r) * ldc + col] = f2bf(acc[i][j][r]);
    }
  }
}

// ---------------------------------------------------------------------------
// Finalize: one block per (image b, caption cap). Cbig is bf16:
// [:, :2048] = attn_raw, [:, 2048:] = capimg, row stride 4096.
// ---------------------------------------------------------------------------
__global__ __launch_bounds__(256) void finalize_kernel(
    const short* __restrict__ Cbig, const float* __restrict__ G,
    const float* __restrict__ w1arr, const int* __restrict__ lens,
    float* __restrict__ out)
{
  const int b   = blockIdx.x;
  const int cap = blockIdx.y;
  const int tid = threadIdx.x;
  __shared__ float att[Sr][Lm + 1];
  __shared__ float cim[Sr][Lm + 1];
  __shared__ float Gs[Sr][Sr + 1];
  __shared__ float w12s[Lm], w2s[Lm];

  const int len = lens[cap];

  for (int i = tid; i < Sr * Lm; i += 256) {
    int s = i >> 5, l = i & 31;
    size_t row = (size_t)(b * Sr + s) * 4096;
    float x = bf2f(Cbig[row + cap * Lm + l]);
    x = x > 0.f ? x : 0.1f * x;        // LeakyReLU(0.1)
    if (l >= len) x = 0.f;             // mask padded words
    att[s][l] = x;
    cim[s][l] = bf2f(Cbig[row + 2048 + cap * Lm + l]);
  }
  for (int i = tid; i < Sr * Sr; i += 256)
    Gs[i / 36][i % 36] = G[(size_t)b * Sr * Sr + i];
  __syncthreads();

  if (tid < Sr) {                      // l2 norm over word dim per region
    float ss = 0.f;
#pragma unroll
    for (int l = 0; l < Lm; l++) { float v = att[tid][l]; ss += v * v; }
    float inv = 1.f / (sqrtf(ss) + EPSF);
#pragma unroll
    for (int l = 0; l < Lm; l++) att[tid][l] *= inv;
  }
  __syncthreads();

  if (tid < Lm) {                      // softmax over regions per word
    int l = tid;
    float m = -1e30f;
#pragma unroll
    for (int s = 0; s < Sr; s++) m = fmaxf(m, att[s][l]);
    m *= SMOOTH;
    float sum = 0.f;
#pragma unroll
    for (int s = 0; s < Sr; s++) {
      float e = expf(SMOOTH * att[s][l] - m);
      att[s][l] = e; sum += e;
    }
    float inv = 1.f / sum;
#pragma unroll
    for (int s = 0; s < Sr; s++) att[s][l] *= inv;
  }
  __syncthreads();

  {                                    // w12, w2 via Gram (8 threads per l)
    int l = tid >> 3, g = tid & 7;
    float w12 = 0.f, w2 = 0.f;
    for (int s = g; s < Sr; s += 8) {
      float a = att[s][l];
      w12 += a * cim[s][l];
      float tt = 0.f;
#pragma unroll
      for (int s2 = 0; s2 < Sr; s2++) tt += Gs[s][s2] * att[s2][l];
      w2 += a * tt;
    }
#pragma unroll
    for (int o = 4; o; o >>= 1) { w12 += __shfl_down(w12, o, 8); w2 += __shfl_down(w2, o, 8); }
    if (g == 0) { w12s[l] = w12; w2s[l] = sqrtf(fmaxf(w2, 0.f)); }
  }
  __syncthreads();

  if (tid < Lm) {
    int l = tid;
    float w1 = w1arr[cap * Lm + l];
    float denom = fmaxf(w1 * w2s[l], EPSF);
    float rs = w12s[l] / denom;
    float z = (l < len) ? rs * LLSE : -1e30f;
    float m = z;
#pragma unroll
    for (int o = 16; o; o >>= 1) m = fmaxf(m, __shfl_xor(m, o, 32));
    float e = expf(z - m);
#pragma unroll
    for (int o = 16; o; o >>= 1) e += __shfl_xor(e, o, 32);
    if (tid == 0) out[(size_t)b * Bn + cap] = (m + logf(e)) / LLSE;
  }
}

// ---------------------------------------------------------------------------
extern "C" void kernel_launch(void* const* d_in, const int* in_sizes, int n_in,
                              void* d_out, int out_size, void* d_ws, size_t ws_size,
                              hipStream_t stream)
{
  const float* images   = (const float*)d_in[0];  // (64,36,1024)
  const float* captions = (const float*)d_in[1];  // (64,32,1024)
  const int*   cap_lens = (const int*)d_in[2];    // (64,)
  const float* W_g      = (const float*)d_in[3];  // (1024,1024)
  float* out = (float*)d_out;                     // (64,64)

  // Workspace (~34.4 MB):
  short* imgbf = (short*)d_ws;                          // 2304*1024 bf16
  short* Bcat  = imgbf + (size_t)2304 * 1024;           // 4096*1024 bf16: [0:2048)=E, [2048:4096)=captions
  short* capbf = Bcat + (size_t)2048 * 1024;
  short* Wbf   = Bcat + (size_t)4096 * 1024;            // 1024*1024 bf16
  short* Cbig  = Wbf + (size_t)1024 * 1024;             // 2304*4096 bf16
  float* Gram  = (float*)(Cbig + (size_t)2304 * 4096);  // 64*36*36 fp32
  float* w1a   = Gram + (size_t)Bn * Sr * Sr;           // 2048 fp32

  // conversions + w1 + gram fused (7680 blocks)
  prep_kernel<<<7680, 256, 0, stream>>>(
      images, imgbf, W_g, Wbf, captions, capbf, w1a, Gram);

  // E = captions @ W_g^T (2048x1024x1024), 32x64 tiles -> 1024 blocks (4/CU)
  mfma_gemm_dbuf<32, 64, 4><<<dim3(1024 / 64, 2048 / 32), 256, 0, stream>>>(
      capbf, Wbf, Bcat, Dd, 1024);
  // Cbig = images @ Bcat^T (2304x4096x1024), 128x64 tiles -> 1152 blocks
  // (LDS 48 KB -> 3 blocks/CU, 12 waves/CU)
  mfma_gemm_dbuf<128, 64, 3><<<dim3(4096 / 64, 2304 / 128), 256, 0, stream>>>(
      imgbf, Bcat, Cbig, Dd, 4096);

  finalize_kernel<<<dim3(Bn, Bn), 256, 0, stream>>>(Cbig, Gram, w1a, cap_lens, out);
}

// Round 7
// 154.270 us; speedup vs baseline: 4.9763x; 1.0423x over previous
//
#include <hip/hip_runtime.h>
#include <cmath>

// Problem constants (fixed by reference)
constexpr int Dd = 1024;   // embed dim
constexpr int Bn = 64;     // n_image == n_caption
constexpr int Sr = 36;     // regions
constexpr int Lm = 32;     // max caption length
constexpr float SMOOTH = 9.0f;
constexpr float LLSE   = 6.0f;
constexpr float EPSF   = 1e-8f;

using frag_ab = __attribute__((ext_vector_type(8))) short;  // 8 bf16 (4 VGPRs)
using frag_cd = __attribute__((ext_vector_type(4))) float;  // 4 fp32 acc

__device__ inline short f2bf(float f) {            // RNE fp32 -> bf16
  union { float f; unsigned u; } v{f};
  unsigned r = v.u + 0x7FFF + ((v.u >> 16) & 1);
  return (short)(r >> 16);
}
__device__ inline float bf2f(short h) {
  union { unsigned u; float f; } v;
  v.u = ((unsigned)(unsigned short)h) << 16;
  return v.f;
}

__device__ inline void gload16(const short* g, short* l) {
  // async global->LDS, 16B/lane; LDS dest = wave-uniform base + lane*16
  __builtin_amdgcn_global_load_lds(
      (__attribute__((address_space(1))) void*)g,
      (__attribute__((address_space(3))) void*)l, 16, 0, 0);
}

// ---------------------------------------------------------------------------
// Fused prep: blockIdx ranges
//   [0, 3328)    : fp32->bf16 conversion of images (2304 blk) + W_g (1024 blk)
//   [3328, 5376) : captions conversion fused with per-row l2 norm (w1)
//   [5376, 7680) : Gram rows, one block per (b, s)
// ---------------------------------------------------------------------------
__global__ __launch_bounds__(256) void prep_kernel(
    const float* __restrict__ images, short* __restrict__ imgbf,
    const float* __restrict__ W_g, short* __restrict__ Wbf,
    const float* __restrict__ captions, short* __restrict__ capbf,
    float* __restrict__ w1, float* __restrict__ G)
{
  const int blk = blockIdx.x;
  const int tid = threadIdx.x;
  __shared__ float4 ref[256];
  __shared__ float wsum[4];

  if (blk < 3328) {
    int i = blk * 1024 + tid * 4;
    const float* src; short* dst;
    if (i < 2304 * 1024) { src = images + i; dst = imgbf + i; }
    else { int j = i - 2304 * 1024; src = W_g + j; dst = Wbf + j; }
    float4 v = *(const float4*)src;
    short4 o;
    o.x = f2bf(v.x); o.y = f2bf(v.y); o.z = f2bf(v.z); o.w = f2bf(v.w);
    *(short4*)dst = o;
  } else if (blk < 5376) {
    const int r = blk - 3328;           // caption row 0..2047
    float4 v = *(const float4*)(captions + (size_t)r * Dd + tid * 4);
    short4 o;
    o.x = f2bf(v.x); o.y = f2bf(v.y); o.z = f2bf(v.z); o.w = f2bf(v.w);
    *(short4*)(capbf + (size_t)r * Dd + tid * 4) = o;
    float s = v.x * v.x + v.y * v.y + v.z * v.z + v.w * v.w;
#pragma unroll
    for (int off = 32; off; off >>= 1) s += __shfl_xor(s, off);
    if ((tid & 63) == 0) wsum[tid >> 6] = s;
    __syncthreads();
    if (tid == 0) w1[r] = sqrtf(wsum[0] + wsum[1] + wsum[2] + wsum[3]);
  } else {
    const int p = blk - 5376;
    const int b = p / Sr, s = p % Sr;
    ref[tid] = ((const float4*)(images + (size_t)(b * Sr + s) * Dd))[tid];
    __syncthreads();
    const int wv = tid >> 6, lane = tid & 63;
    for (int s2 = wv; s2 < Sr; s2 += 4) {
      const float4* row2 = (const float4*)(images + (size_t)(b * Sr + s2) * Dd);
      float acc = 0.f;
#pragma unroll
      for (int j = 0; j < 4; j++) {
        float4 a = ref[lane + j * 64];
        float4 c = row2[lane + j * 64];
        acc += a.x * c.x + a.y * c.y + a.z * c.z + a.w * c.w;
      }
#pragma unroll
      for (int o = 32; o; o >>= 1) acc += __shfl_xor(acc, o);
      if (lane == 0) G[(size_t)b * Sr * Sr + s * Sr + s2] = acc;
    }
  }
}

// ---------------------------------------------------------------------------
// GEMM1 (E = cap @ W^T): 256-thr template kernel from R6, 32x64 tile, BK=64,
// double-buffered, XOR-swizzled LDS.
// ---------------------------------------------------------------------------
template <int BM, int BN, int MINW>
__global__ __launch_bounds__(256, MINW) void mfma_gemm_dbuf(
    const short* __restrict__ A, const short* __restrict__ B,
    short* __restrict__ C, int K, int ldc)
{
  constexpr int FI = BM / 32;
  constexpr int FJ = BN / 32;
  __shared__ __align__(16) short LA[2][BM * 64];
  __shared__ __align__(16) short LB[2][BN * 64];

  const int t    = threadIdx.x;
  const int lane = t & 63;
  const int w    = t >> 6;
  const int wm   = w >> 1;
  const int wn   = w & 1;
  const int m0 = blockIdx.y * BM;
  const int n0 = blockIdx.x * BN;

  const int rIn = t >> 3;
  const int ch  = (t & 7) ^ (rIn & 7);
  const short* gA = A + (size_t)(m0 + rIn) * K + ch * 8;
  const short* gB = B + (size_t)(n0 + rIn) * K + ch * 8;

  const int fr = lane & 15;
  const int fq = lane >> 4;
  const int p0 = fq ^ (fr & 7);

  frag_cd acc[FI][FJ] = {};

  auto stage = [&](int buf, int k0) {
#pragma unroll
    for (int j = 0; j < BM / 32; j++)
      gload16(gA + (size_t)j * 32 * K + k0, &LA[buf][j * 2048 + w * 512]);
#pragma unroll
    for (int j = 0; j < BN / 32; j++)
      gload16(gB + (size_t)j * 32 * K + k0, &LB[buf][j * 2048 + w * 512]);
  };

  stage(0, 0);
  int cur = 0;
  for (int k0 = 0; k0 < K; k0 += 64) {
    __syncthreads();
    if (k0 + 64 < K) stage(cur ^ 1, k0 + 64);

    const short* aBase = &LA[cur][(wm * (FI * 16) + fr) * 64];
    const short* bBase = &LB[cur][(wn * (FJ * 16) + fr) * 64];
#pragma unroll
    for (int th = 0; th < 2; th++) {
      const int pa = p0 ^ (th * 4);
      frag_ab af[FI], bf[FJ];
#pragma unroll
      for (int i = 0; i < FI; i++)
        af[i] = *(const frag_ab*)(aBase + i * 16 * 64 + pa * 8);
#pragma unroll
      for (int j = 0; j < FJ; j++)
        bf[j] = *(const frag_ab*)(bBase + j * 16 * 64 + pa * 8);
#pragma unroll
      for (int i = 0; i < FI; i++)
#pragma unroll
        for (int j = 0; j < FJ; j++)
          acc[i][j] = __builtin_amdgcn_mfma_f32_16x16x32_bf16(
              af[i], bf[j], acc[i][j], 0, 0, 0);
    }
    cur ^= 1;
  }

#pragma unroll
  for (int i = 0; i < FI; i++) {
    int row = m0 + wm * (FI * 16) + i * 16 + fq * 4;
#pragma unroll
    for (int j = 0; j < FJ; j++) {
      int col = n0 + wn * (FJ * 16) + j * 16 + fr;
#pragma unroll
      for (int r = 0; r < 4; r++)
        C[(size_t)(row + r) * ldc + col] = f2bf(acc[i][j][r]);
    }
  }
}

// ---------------------------------------------------------------------------
// GEMM2 (Cbig = images @ Bcat^T): 128-thread / 2-wave blocks, block tile
// 128x64, WAVE tile 64x64 (FI=FJ=4 -> 0.031 LDS-B/FLOP, m97-class), BK=64,
// single-buffer (dbuf measured neutral: R5, m99), XOR-swizzled LDS
// (conflict-free b128 frag reads). LDS 24.6 KB -> 6 blocks/CU = 12 waves/CU:
// high occupancy AND high per-wave intensity simultaneously.
// ---------------------------------------------------------------------------
__global__ __launch_bounds__(128, 3) void gemm2_w64(
    const short* __restrict__ A, const short* __restrict__ B,
    short* __restrict__ C, int K, int ldc)
{
  __shared__ __align__(16) short As[128 * 64];
  __shared__ __align__(16) short Bs[64 * 64];

  const int t    = threadIdx.x;     // 0..127
  const int lane = t & 63;
  const int w    = t >> 6;          // wave 0..1 (m-halves)
  const int m0 = blockIdx.y * 128;
  const int n0 = blockIdx.x * 64;

  // staging: issue j covers 16 rows; thread t -> rowIn = t>>3, stores global
  // chunk (t&7)^(rowIn&7) at position t&7 (swizzle; global coalesced: 8
  // lanes cover a full 128B row).
  const int rIn = t >> 3;
  const int ch  = (t & 7) ^ (rIn & 7);
  const short* gA = A + (size_t)(m0 + rIn) * K + ch * 8;
  const short* gB = B + (size_t)(n0 + rIn) * K + ch * 8;

  const int fr = lane & 15;
  const int fq = lane >> 4;
  const int p0 = fq ^ (fr & 7);

  frag_cd acc[4][4] = {};

  for (int k0 = 0; k0 < K; k0 += 64) {
    __syncthreads();                 // prev-iter LDS readers done
#pragma unroll
    for (int j = 0; j < 8; j++)      // A: 128 rows, 16 per issue
      gload16(gA + (size_t)j * 16 * K + k0, As + j * 1024 + w * 512);
#pragma unroll
    for (int j = 0; j < 4; j++)      // B: 64 rows
      gload16(gB + (size_t)j * 16 * K + k0, Bs + j * 1024 + w * 512);
    __syncthreads();                 // barrier drains vmcnt -> tile published

    const short* aBase = As + (w * 64 + fr) * 64;
    const short* bBase = Bs + fr * 64;
#pragma unroll
    for (int th = 0; th < 2; th++) {
      const int pa = p0 ^ (th * 4);  // swizzled chunk pos for this k-half
      frag_ab af[4], bf[4];
#pragma unroll
      for (int i = 0; i < 4; i++)
        af[i] = *(const frag_ab*)(aBase + i * 16 * 64 + pa * 8);
#pragma unroll
      for (int j = 0; j < 4; j++)
        bf[j] = *(const frag_ab*)(bBase + j * 16 * 64 + pa * 8);
#pragma unroll
      for (int i = 0; i < 4; i++)
#pragma unroll
        for (int j = 0; j < 4; j++)
          acc[i][j] = __builtin_amdgcn_mfma_f32_16x16x32_bf16(
              af[i], bf[j], acc[i][j], 0, 0, 0);
    }
  }

  // C/D layout: col = lane&15, row = (lane>>4)*4 + reg  [verified m89/m91]
#pragma unroll
  for (int i = 0; i < 4; i++) {
    int row = m0 + w * 64 + i * 16 + fq * 4;
#pragma unroll
    for (int j = 0; j < 4; j++) {
      int col = n0 + j * 16 + fr;
#pragma unroll
      for (int r = 0; r < 4; r++)
        C[(size_t)(row + r) * ldc + col] = f2bf(acc[i][j][r]);
    }
  }
}

// ---------------------------------------------------------------------------
// Finalize v2: block = (image b, 4 captions); ONE WAVE PER (b,cap) PAIR.
// Lane layout: l = lane&31 (word), s0 = lane>>5 (s-parity / s-half split).
// a-vector kept in registers (36 VGPRs); Gram broadcast-read from LDS.
// ---------------------------------------------------------------------------
__global__ __launch_bounds__(256) void finalize_kernel(
    const short* __restrict__ Cbig, const float* __restrict__ G,
    const float* __restrict__ w1arr, const int* __restrict__ lens,
    float* __restrict__ out)
{
  const int b   = blockIdx.x;        // image
  const int cg  = blockIdx.y;        // caption group of 4
  const int t   = threadIdx.x;
  const int wv  = t >> 6;            // wave -> caption within group
  const int lane = t & 63;
  const int cap = cg * 4 + wv;
  const int l = lane & 31;
  const int s0 = lane >> 5;

  __shared__ float att[4][Sr][Lm];   // fp32 working attn, per wave
  __shared__ short cims[4][Sr][Lm];  // bf16 cap.img dots, per wave
  __shared__ float Gs[Sr][Sr];       // Gram, shared across waves

  for (int i = t; i < Sr * Sr; i += 256)
    Gs[i / Sr][i % Sr] = G[(size_t)b * Sr * Sr + i];

  const int len = lens[cap];

  // load + leaky-relu + mask (2 s-rows per step: s = 2k + s0)
#pragma unroll
  for (int k = 0; k < 18; k++) {
    int s = k * 2 + s0;
    size_t row = (size_t)(b * Sr + s) * 4096;
    float x = bf2f(Cbig[row + cap * Lm + l]);
    x = x > 0.f ? x : 0.1f * x;
    if (l >= len) x = 0.f;
    att[wv][s][l] = x;
    cims[wv][s][l] = Cbig[row + 2048 + cap * Lm + l];
  }
  __syncthreads();

  // l2 norm over words l, per region s (half-wave reduction, width 32)
#pragma unroll
  for (int k = 0; k < 18; k++) {
    int s = k * 2 + s0;
    float v = att[wv][s][l];
    float ss = v * v;
#pragma unroll
    for (int o = 16; o; o >>= 1) ss += __shfl_xor(ss, o);
    att[wv][s][l] = v * (1.f / (sqrtf(ss) + EPSF));
  }
  __syncthreads();

  // softmax over regions s, per word l (half 0 only)
  if (s0 == 0) {
    float m = -1e30f;
#pragma unroll
    for (int s = 0; s < Sr; s++) m = fmaxf(m, att[wv][s][l]);
    m *= SMOOTH;
    float sum = 0.f;
#pragma unroll
    for (int s = 0; s < Sr; s++) {
      float e = expf(SMOOTH * att[wv][s][l] - m);
      att[wv][s][l] = e; sum += e;
    }
    float inv = 1.f / sum;
#pragma unroll
    for (int s = 0; s < Sr; s++) att[wv][s][l] *= inv;
  }
  __syncthreads();

  // a into registers; w12 & w2 = a^T G a with outer s split across halves
  float a_reg[Sr];
#pragma unroll
  for (int s = 0; s < Sr; s++) a_reg[s] = att[wv][s][l];
  float w12 = 0.f, w2 = 0.f;
  for (int s = s0 * 18; s < s0 * 18 + 18; s++) {
    float a = a_reg[s];
    w12 += a * bf2f(cims[wv][s][l]);
    float tt = 0.f;
    const float4* grow = (const float4*)Gs[s];
#pragma unroll
    for (int q = 0; q < 9; q++) {
      float4 g = grow[q];                        // broadcast read
      tt += g.x * a_reg[q * 4] + g.y * a_reg[q * 4 + 1] +
            g.z * a_reg[q * 4 + 2] + g.w * a_reg[q * 4 + 3];
    }
    w2 += a * tt;
  }
  w12 += __shfl_xor(w12, 32);
  w2  += __shfl_xor(w2, 32);

  // cosine + LogSumExp over valid words (width-32 reduce; halves identical)
  float w1v = w1arr[cap * Lm + l];
  float denom = fmaxf(w1v * sqrtf(fmaxf(w2, 0.f)), EPSF);
  float rs = w12 / denom;
  float z = (l < len) ? rs * LLSE : -1e30f;
  float m = z;
#pragma unroll
  for (int o = 16; o; o >>= 1) m = fmaxf(m, __shfl_xor(m, o));
  float e = expf(z - m);
#pragma unroll
  for (int o = 16; o; o >>= 1) e += __shfl_xor(e, o);
  if (lane == 0) out[(size_t)b * Bn + cap] = (m + logf(e)) / LLSE;
}

// ---------------------------------------------------------------------------
extern "C" void kernel_launch(void* const* d_in, const int* in_sizes, int n_in,
                              void* d_out, int out_size, void* d_ws, size_t ws_size,
                              hipStream_t stream)
{
  const float* images   = (const float*)d_in[0];  // (64,36,1024)
  const float* captions = (const float*)d_in[1];  // (64,32,1024)
  const int*   cap_lens = (const int*)d_in[2];    // (64,)
  const float* W_g      = (const float*)d_in[3];  // (1024,1024)
  float* out = (float*)d_out;                     // (64,64)

  // Workspace (~34.4 MB):
  short* imgbf = (short*)d_ws;                          // 2304*1024 bf16
  short* Bcat  = imgbf + (size_t)2304 * 1024;           // 4096*1024 bf16: [0:2048)=E, [2048:4096)=captions
  short* capbf = Bcat + (size_t)2048 * 1024;
  short* Wbf   = Bcat + (size_t)4096 * 1024;            // 1024*1024 bf16
  short* Cbig  = Wbf + (size_t)1024 * 1024;             // 2304*4096 bf16
  float* Gram  = (float*)(Cbig + (size_t)2304 * 4096);  // 64*36*36 fp32
  float* w1a   = Gram + (size_t)Bn * Sr * Sr;           // 2048 fp32

  // conversions + w1 + gram fused (7680 blocks)
  prep_kernel<<<7680, 256, 0, stream>>>(
      images, imgbf, W_g, Wbf, captions, capbf, w1a, Gram);

  // E = captions @ W_g^T (2048x1024x1024), 32x64 tiles -> 1024 blocks
  mfma_gemm_dbuf<32, 64, 4><<<dim3(1024 / 64, 2048 / 32), 256, 0, stream>>>(
      capbf, Wbf, Bcat, Dd, 1024);
  // Cbig = images @ Bcat^T (2304x4096x1024): 128x64 blocks, 2 waves,
  // wave tile 64x64 -> 1152 blocks, 6 blocks/CU
  gemm2_w64<<<dim3(4096 / 64, 2304 / 128), 128, 0, stream>>>(
      imgbf, Bcat, Cbig, Dd, 4096);

  // finalize: block = image x 4 captions, one wave per (b,cap)
  finalize_kernel<<<dim3(Bn, Bn / 4), 256, 0, stream>>>(
      Cbig, Gram, w1a, cap_lens, out);
}